// Round 11
// baseline (1518.536 us; speedup 1.0000x reference)
//
#include <hip/hip_runtime.h>

typedef unsigned short ushort;
typedef unsigned int uint;
typedef __attribute__((ext_vector_type(8))) short short8;
typedef __attribute__((ext_vector_type(4))) float floatx4;

#define NTOT   65536
#define CH     64
#define NLAYER 4
#define NEDGE  1048576
#define EPSV   1e-5f

// staged-weight arena element offsets (order = d_in[3..32]); 2-D weights stored TRANSPOSED [n][k]
#define OW_EMB 0
#define OB_EMB 3072
#define OW_PE  3120
#define OB_PE  3376
#define OG_PEN 3392
#define OB_PEN 3408
#define OW_G1  3424
#define OB_G1  19808
#define OW_G2  20064
#define OB_G2  36448
#define OW_Q   36704
#define OB_Q   53088
#define OW_K   53344
#define OB_K   69728
#define OW_V   69984
#define OB_V   86368
#define OW_O   86624
#define OB_O   103008
#define ON1G   103264
#define ON1B   103520
#define ON2G   103776
#define ON2B   104032
#define ON3G   104288
#define ON3B   104544
#define OW_M1  104800
#define OB_M1  137568
#define OW_M2  138080
#define OB_M2  170848
#define OW_H   171104
#define OB_H   179296
#define TOTW   179424

__device__ __forceinline__ float bf2f(ushort u){ return __uint_as_float(((uint)u) << 16); }
__device__ __forceinline__ ushort f2bf(float f){
    uint u = __float_as_uint(f);
    uint r = (u + 0x7fffu + ((u >> 16) & 1u)) >> 16;
    return (ushort)r;
}
__device__ __forceinline__ float2 bfp2(uint w){
    return make_float2(__uint_as_float(w << 16), __uint_as_float(w & 0xffff0000u));
}
__device__ __forceinline__ short8 ldf(const ushort* p){ return *(const short8*)p; }
__device__ __forceinline__ floatx4 mfma16(short8 a, short8 b, floatx4 c){
    return __builtin_amdgcn_mfma_f32_16x16x32_bf16(a, b, c, 0, 0, 0);
}
// compute per-channel BN (a,b) into sf[128]; ident=1 -> identity
__device__ __forceinline__ void bnfin(float* sf, const float* st, const ushort* g,
                                      const ushort* b, int ident, int t){
    if (t < 64){
        float a, bb;
        if (ident){ a = 1.f; bb = 0.f; }
        else {
            float mu  = st[t] * (1.f / NTOT);
            float var = st[64 + t] * (1.f / NTOT) - mu * mu;
            a = rsqrtf(var + EPSV) * bf2f(g[t]);
            bb = bf2f(b[t]) - mu * a;
        }
        sf[t] = a; sf[64 + t] = bb;
    }
}

// ---------------- dtype probe: 1=bf16 inputs, 0=fp32 inputs ----------------
__global__ void detect_k(const uint* __restrict__ x, int* __restrict__ flag){
    int lane = threadIdx.x;
    uint w = x[lane];
    uint e = (w >> 7) & 0xffu;
    int ok = (e >= 100u && e <= 140u) ? 1 : 0;
    unsigned long long m = __ballot(ok);
    if (lane == 0) flag[0] = (__popcll(m) >= 48) ? 1 : 0;
}

// ---------------- convert/copy weights into bf16 arena (2-D weights transposed) ----------------
struct WPtrs { const void* p[30]; };

__global__ void convall_k(WPtrs ptrs, ushort* __restrict__ dst, const int* __restrict__ flag){
    const int offs[31] = {0,3072,3120,3376,3392,3408,3424,19808,20064,36448,36704,
                          53088,53344,69728,69984,86368,86624,103008,103264,103520,
                          103776,104032,104288,104544,104800,137568,138080,170848,
                          171104,179296,179424};
    const int kdt[30] = {64,0,16,0,0,0, 64,0,64,0, 64,0,64,0,64,0,64,0,
                         0,0,0,0,0,0, 64,0,128,0, 64,0};
    const int ndt[30] = {48,0,16,0,0,0, 64,0,64,0, 64,0,64,0,64,0,64,0,
                         0,0,0,0,0,0, 128,0,64,0, 128,0};
    int i = blockIdx.x * blockDim.x + threadIdx.x;
    if (i >= TOTW) return;
    int s = 0;
    while (s < 29 && i >= offs[s + 1]) ++s;
    int j = i - offs[s];
    int srcj = j;
    int K = kdt[s];
    if (K > 0){
        int N = ndt[s], KN = K * N;
        int l = j / KN, r = j - l * KN;
        int n = r / K, k2 = r - n * K;
        srcj = l * KN + k2 * N + n;
    }
    if (*flag) dst[i] = ((const ushort*)ptrs.p[s])[srcj];
    else       dst[i] = f2bf(((const float*)ptrs.p[s])[srcj]);
}

// ---------------- BN stats over pe ----------------
__global__ void pe_stats_k(const void* __restrict__ peraw, const int* __restrict__ flag,
                           float* __restrict__ stats){
    int bf = *flag;
    int t = threadIdx.x;
    int c = t & 15, rb = t >> 4;
    int row0 = blockIdx.x * 256;
    float s = 0.f, ss = 0.f;
    for (int i = 0; i < 16; ++i){
        int r = row0 + rb + 16 * i;
        size_t idx = (size_t)r * 16 + c;
        float v = bf ? bf2f(((const ushort*)peraw)[idx]) : ((const float*)peraw)[idx];
        s += v; ss += v * v;
    }
    __shared__ float red[256];
    red[t] = s; __syncthreads();
    if (t < 16){ float tot = 0.f; for (int j = 0; j < 16; ++j) tot += red[t + 16 * j]; atomicAdd(&stats[t], tot); }
    __syncthreads();
    red[t] = ss; __syncthreads();
    if (t < 16){ float tot = 0.f; for (int j = 0; j < 16; ++j) tot += red[t + 16 * j]; atomicAdd(&stats[64 + t], tot); }
}

__global__ void fin_k(const float* __restrict__ stats, const ushort* __restrict__ g,
                      const ushort* __restrict__ b, float* __restrict__ fin, int nch){
    int c = threadIdx.x;
    if (c >= nch) return;
    float mu  = stats[c] * (1.f / NTOT);
    float var = stats[64 + c] * (1.f / NTOT) - mu * mu;
    float a = rsqrtf(var + EPSV) * bf2f(g[c]);
    fin[c] = a;
    fin[64 + c] = bf2f(b[c]) - mu * a;
}

// ---------------- embedding, MFMA version ----------------
__global__ void embed_k(const void* __restrict__ xraw, const void* __restrict__ peraw,
                        const int* __restrict__ flag, const ushort* __restrict__ wsa,
                        const float* __restrict__ finpe, ushort* __restrict__ hout){
    __shared__ __align__(16) ushort xb[64 * 72];
    __shared__ __align__(16) ushort pen[64 * 24];
    __shared__ __align__(16) ushort Wes[48 * 72];
    __shared__ __align__(16) ushort Wps[16 * 24];
    int bf = *flag;
    int t = threadIdx.x;
    int row0 = blockIdx.x * 64;
    if (bf){
        const uint* xsrc = (const uint*)((const ushort*)xraw + (size_t)row0 * 64);
        for (int i = t; i < 2048; i += 256){
            int r = i >> 5, u = i & 31;
            ((uint*)(xb + r * 72))[u] = xsrc[i];
        }
    } else {
        const float4* xsrc = (const float4*)((const float*)xraw + (size_t)row0 * 64);
        for (int i = t; i < 1024; i += 256){
            int r = i >> 4, u = i & 15;
            float4 f = xsrc[i];
            ((uint*)(xb + r * 72))[2 * u]     = (uint)f2bf(f.x) | ((uint)f2bf(f.y) << 16);
            ((uint*)(xb + r * 72))[2 * u + 1] = (uint)f2bf(f.z) | ((uint)f2bf(f.w) << 16);
        }
    }
    for (int i = t; i < 1024; i += 256){
        int r = i >> 4, k = i & 15;
        size_t idx = (size_t)(row0 + r) * 16 + k;
        float v = bf ? bf2f(((const ushort*)peraw)[idx]) : ((const float*)peraw)[idx];
        pen[r * 24 + k] = f2bf(v * finpe[k] + finpe[64 + k]);
    }
    for (int i = t; i < 1536; i += 256){
        int r = i >> 5, u = i & 31;
        ((uint*)(Wes + r * 72))[u] = ((const uint*)(wsa + OW_EMB))[i];
    }
    {
        int r = t >> 4, k = t & 15;
        Wps[r * 24 + k] = wsa[OW_PE + t];
    }
    __syncthreads();
    int w = t >> 6, l = t & 63, m = l & 15, quad = l >> 4;
    const short8 zero8 = {0, 0, 0, 0, 0, 0, 0, 0};
    const floatx4 zf4 = {0.f, 0.f, 0.f, 0.f};
    const ushort* ap = xb + (16 * w + m) * 72 + quad * 8;
    short8 a0 = ldf(ap), a1 = ldf(ap + 32);
    short8 ape = (quad < 2) ? ldf(pen + (16 * w + m) * 24 + quad * 8) : zero8;
    #pragma unroll
    for (int nt = 0; nt < 4; ++nt){
        floatx4 c = zf4;
        float bias;
        if (nt < 3){
            const ushort* bp = Wes + (nt * 16 + m) * 72 + quad * 8;
            c = mfma16(a0, ldf(bp), c);
            c = mfma16(a1, ldf(bp + 32), c);
            bias = bf2f(wsa[OB_EMB + nt * 16 + m]);
        } else {
            short8 bpe = (quad < 2) ? ldf(Wps + m * 24 + quad * 8) : zero8;
            c = mfma16(ape, bpe, c);
            bias = bf2f(wsa[OB_PE + m]);
        }
        #pragma unroll
        for (int r = 0; r < 4; ++r)
            hout[(size_t)(row0 + 16 * w + quad * 4 + r) * 64 + nt * 16 + m] = f2bf(c[r] + bias);
    }
}

// ---------------- CSR build: hist -> scan -> scatter ----------------
__global__ void hist_k(const int* __restrict__ dst, int* __restrict__ cnt){
    int stride = gridDim.x * blockDim.x;
    for (int e = blockIdx.x * blockDim.x + threadIdx.x; e < NEDGE; e += stride)
        atomicAdd(&cnt[dst[e]], 1);
}

__global__ void scan_k(const int* __restrict__ cnt, int* __restrict__ offs, int* __restrict__ cur){
    int t = threadIdx.x;
    int base0 = t * 64;
    int s = 0;
    for (int i = 0; i < 64; ++i) s += cnt[base0 + i];
    __shared__ int pref[1024];
    pref[t] = s; __syncthreads();
    for (int off = 1; off < 1024; off <<= 1){
        int v = (t >= off) ? pref[t - off] : 0;
        __syncthreads();
        pref[t] += v;
        __syncthreads();
    }
    int run = pref[t] - s;
    for (int i = 0; i < 64; ++i){
        offs[base0 + i] = run;
        cur[base0 + i]  = run;
        run += cnt[base0 + i];
    }
    if (t == 1023) offs[65536] = run;
}

__global__ void scatter_k(const int* __restrict__ src, const int* __restrict__ dst,
                          int* __restrict__ cur, int* __restrict__ csr){
    int stride = gridDim.x * blockDim.x;
    for (int e = blockIdx.x * blockDim.x + threadIdx.x; e < NEDGE; e += stride){
        int p = atomicAdd(&cur[dst[e]], 1);
        csr[p] = src[e];
    }
}

// ======== fused AGG + GIN-MLP + QKV, 64-row tiles, 4 waves ========
// agg gathered directly into the As LDS tile (BN-on-read affine); saves the z
// round-trip (8 MB write + 8 MB read per layer) and a dispatch.
__global__ void ginqkv_k(const ushort* __restrict__ h,
                         const int* __restrict__ offs, const int* __restrict__ csr,
                         const float* __restrict__ st3, const ushort* __restrict__ g3,
                         const ushort* __restrict__ b3, int ident,
                         const ushort* __restrict__ W1, const ushort* __restrict__ b1,
                         const ushort* __restrict__ W2, const ushort* __restrict__ b2,
                         const ushort* __restrict__ Wq, const ushort* __restrict__ bq,
                         const ushort* __restrict__ Wk, const ushort* __restrict__ bk,
                         const ushort* __restrict__ Wv, const ushort* __restrict__ bv,
                         ushort* __restrict__ zout, ushort* __restrict__ qo,
                         ushort* __restrict__ ko, ushort* __restrict__ vo,
                         float* __restrict__ stats){
    __shared__ __align__(16) ushort As[64 * 72];
    __shared__ __align__(16) ushort Hs[64 * 72];
    __shared__ __align__(16) ushort W1s[64 * 72];
    __shared__ __align__(16) ushort W2s[64 * 72];
    __shared__ __align__(16) ushort Wqs[64 * 72];
    __shared__ __align__(16) ushort Wks[64 * 72];
    __shared__ __align__(16) ushort Wvs[64 * 72];
    __shared__ float sb[128];
    __shared__ float sf[128];
    int t = threadIdx.x;
    int row0 = blockIdx.x * 64;
    bnfin(sf, st3, g3, b3, ident, t);
    if (t < 128) sb[t] = 0.f;
    __syncthreads();
    // stage weights + bn(h) tile
    for (int i = t; i < 2048; i += 256){
        int r = i >> 5, u = i & 31;
        uint hv = ((const uint*)(h + (size_t)row0 * 64))[i];
        int c0 = u * 2;
        float2 p = bfp2(hv);
        ((uint*)(Hs + r * 72))[u] = (uint)f2bf(p.x * sf[c0] + sf[64 + c0])
                                  | ((uint)f2bf(p.y * sf[c0 + 1] + sf[64 + c0 + 1]) << 16);
        ((uint*)(W1s + r * 72))[u] = ((const uint*)W1)[i];
        ((uint*)(W2s + r * 72))[u] = ((const uint*)W2)[i];
        ((uint*)(Wqs + r * 72))[u] = ((const uint*)Wq)[i];
        ((uint*)(Wks + r * 72))[u] = ((const uint*)Wk)[i];
        ((uint*)(Wvs + r * 72))[u] = ((const uint*)Wv)[i];
    }
    // fused GIN aggregate: gather CSR neighbors directly into As
    {
        int w = t >> 6, l = t & 63;
        int c2 = l & 31;
        const uint* hp = (const uint*)h;
        for (int it = 0; it < 8; ++it){
            int nl = it * 8 + w * 2 + (l >> 5);
            int node = row0 + nl;
            int beg = offs[node], end = offs[node + 1];
            float2 s = bfp2(hp[(size_t)node * 32 + c2]);
            for (int i = beg; i < end; ++i){
                int sn = csr[i];
                float2 p = bfp2(hp[(size_t)sn * 32 + c2]);
                s.x += p.x; s.y += p.y;
            }
            float n = (float)(1 + end - beg);
            int c0 = c2 * 2;
            float o0 = sf[c0] * s.x + n * sf[64 + c0];
            float o1 = sf[c0 + 1] * s.y + n * sf[64 + c0 + 1];
            ((uint*)(As + nl * 72))[c2] = (uint)f2bf(o0) | ((uint)f2bf(o1) << 16);
        }
    }
    __syncthreads();
    int w = t >> 6, l = t & 63, m = l & 15, q4 = l >> 4;
    const ushort* ap = As + (16 * w + m) * 72 + q4 * 8;
    short8 a0 = ldf(ap), a1 = ldf(ap + 32);
    const ushort* hpp = Hs + (16 * w + m) * 72 + q4 * 8;
    short8 h0 = ldf(hpp), h1 = ldf(hpp + 32);
    floatx4 acc[4];
    #pragma unroll
    for (int nt = 0; nt < 4; ++nt){
        const ushort* bp = W1s + (nt * 16 + m) * 72 + q4 * 8;
        floatx4 c = {0.f, 0.f, 0.f, 0.f};
        c = mfma16(a0, ldf(bp), c);
        c = mfma16(a1, ldf(bp + 32), c);
        acc[nt] = c;
    }
    #pragma unroll
    for (int nt = 0; nt < 4; ++nt){
        float bv = bf2f(b1[nt * 16 + m]);
        #pragma unroll
        for (int r = 0; r < 4; ++r)
            As[(16 * w + q4 * 4 + r) * 72 + nt * 16 + m] = f2bf(fmaxf(acc[nt][r] + bv, 0.f));
    }
    const ushort* ap2 = As + (16 * w + m) * 72 + q4 * 8;
    short8 t0 = ldf(ap2), t1 = ldf(ap2 + 32);
    #pragma unroll
    for (int nt = 0; nt < 4; ++nt){
        const ushort* bp = W2s + (nt * 16 + m) * 72 + q4 * 8;
        floatx4 c = {0.f, 0.f, 0.f, 0.f};
        c = mfma16(t0, ldf(bp), c);
        c = mfma16(t1, ldf(bp + 32), c);
        float bv = bf2f(b2[nt * 16 + m]);
        float vs = 0.f, vss = 0.f;
        #pragma unroll
        for (int r = 0; r < 4; ++r){
            int lr = 16 * w + q4 * 4 + r;
            float val = c[r] + bv + bf2f(Hs[lr * 72 + nt * 16 + m]);
            zout[(size_t)(row0 + lr) * 64 + nt * 16 + m] = f2bf(val);
            vs += val; vss += val * val;
        }
        vs  += __shfl_xor(vs, 16, 64);  vs  += __shfl_xor(vs, 32, 64);
        vss += __shfl_xor(vss, 16, 64); vss += __shfl_xor(vss, 32, 64);
        if (q4 == 0){
            atomicAdd(&sb[nt * 16 + m], vs);
            atomicAdd(&sb[64 + nt * 16 + m], vss);
        }
    }
    ushort* outs[3] = {qo, ko, vo};
    const ushort* bias[3] = {bq, bk, bv};
    const ushort* wmats[3] = {Wqs, Wks, Wvs};
    #pragma unroll
    for (int o = 0; o < 3; ++o){
        #pragma unroll
        for (int nt = 0; nt < 4; ++nt){
            const ushort* bp = wmats[o] + (nt * 16 + m) * 72 + q4 * 8;
            floatx4 c = {0.f, 0.f, 0.f, 0.f};
            c = mfma16(h0, ldf(bp), c);
            c = mfma16(h1, ldf(bp + 32), c);
            float bv2 = bf2f(bias[o][nt * 16 + m]);
            #pragma unroll
            for (int r = 0; r < 4; ++r)
                outs[o][(size_t)(row0 + 16 * w + q4 * 4 + r) * 64 + nt * 16 + m] = f2bf(c[r] + bv2);
        }
    }
    __syncthreads();
    if (t < 64){
        atomicAdd(&stats[t], sb[t]);
        atomicAdd(&stats[64 + t], sb[64 + t]);
    }
}

// ---------------- MFMA flash attention, shift-free softmax ----------------
__global__ void attn_k(ushort* __restrict__ q, const ushort* __restrict__ k,
                       const ushort* __restrict__ v){
    __shared__ __align__(16) ushort Ks[512 * 24];
    __shared__ __align__(16) ushort Vt[16 * 536];
    int t = threadIdx.x;
    int g = blockIdx.x >> 2, head = blockIdx.x & 3;
    int base = g * 512;
    for (int i = t; i < 4096; i += 256){
        int n = i >> 3, u = i & 7;
        uint kw = ((const uint*)(k + (size_t)(base + n) * 64 + head * 16))[u];
        uint vw = ((const uint*)(v + (size_t)(base + n) * 64 + head * 16))[u];
        float2 kf = bfp2(kw);
        Ks[n * 24 + 2 * u]     = f2bf(kf.x * 0.25f);
        Ks[n * 24 + 2 * u + 1] = f2bf(kf.y * 0.25f);
        Vt[(2 * u) * 536 + n]     = (ushort)(vw & 0xffffu);
        Vt[(2 * u + 1) * 536 + n] = (ushort)(vw >> 16);
    }
    __syncthreads();
    int w = t >> 6, l = t & 63, m16 = l & 15, quad = l >> 4;
    const short8 zero8 = {0, 0, 0, 0, 0, 0, 0, 0};
    const floatx4 zf4 = {0.f, 0.f, 0.f, 0.f};
    int key1 = ((m16 >> 2) << 3) + (m16 & 3);

    for (int qi = 0; qi < 8; ++qi){
        int qt = w * 8 + qi;
        int qrow = base + qt * 16 + m16;
        short8 qf = zero8;
        if (quad < 2) qf = ldf(q + (size_t)qrow * 64 + head * 16 + quad * 8);
        floatx4 O = zf4;
        float ll = 0.f;
        for (int kg = 0; kg < 16; ++kg){
            int kb = kg * 32;
            short8 af1 = zero8, af2 = zero8;
            if (quad < 2){
                const ushort* kp = Ks + (kb + key1) * 24 + quad * 8;
                af1 = ldf(kp);
                af2 = ldf(kp + 96);
            }
            floatx4 s1 = mfma16(af1, qf, zf4);
            floatx4 s2 = mfma16(af2, qf, zf4);
            float p0 = __expf(fminf(s1[0], 50.f)), p1 = __expf(fminf(s1[1], 50.f));
            float p2 = __expf(fminf(s1[2], 50.f)), p3 = __expf(fminf(s1[3], 50.f));
            float p4 = __expf(fminf(s2[0], 50.f)), p5 = __expf(fminf(s2[1], 50.f));
            float p6 = __expf(fminf(s2[2], 50.f)), p7 = __expf(fminf(s2[3], 50.f));
            ll += ((p0 + p1) + (p2 + p3)) + ((p4 + p5) + (p6 + p7));
            short8 pf;
            pf[0] = (short)f2bf(p0); pf[1] = (short)f2bf(p1);
            pf[2] = (short)f2bf(p2); pf[3] = (short)f2bf(p3);
            pf[4] = (short)f2bf(p4); pf[5] = (short)f2bf(p5);
            pf[6] = (short)f2bf(p6); pf[7] = (short)f2bf(p7);
            short8 vf = ldf(Vt + m16 * 536 + kb + quad * 8);
            O = mfma16(vf, pf, O);
        }
        ll += __shfl_xor(ll, 16, 64);
        ll += __shfl_xor(ll, 32, 64);
        float inv = 1.f / ll;
        uint lo = (uint)f2bf(O[0] * inv) | ((uint)f2bf(O[1] * inv) << 16);
        uint hi = (uint)f2bf(O[2] * inv) | ((uint)f2bf(O[3] * inv) << 16);
        uint2 st = {lo, hi};
        *(uint2*)(q + (size_t)qrow * 64 + head * 16 + quad * 4) = st;
    }
}

// ---------------- O-projection + bn(h) residual + BN2 stats (in-place on o) ----------------
__global__ void oproj_k(ushort* __restrict__ o, const ushort* __restrict__ h,
                        const float* __restrict__ st3, const ushort* __restrict__ g3,
                        const ushort* __restrict__ b3, int ident,
                        const ushort* __restrict__ Wo, const ushort* __restrict__ bo,
                        float* __restrict__ stats){
    __shared__ __align__(16) ushort As[64 * 72];
    __shared__ __align__(16) ushort Ws[64 * 72];
    __shared__ float sb[128];
    __shared__ float sf[128];
    int t = threadIdx.x;
    int row0 = blockIdx.x * 64;
    bnfin(sf, st3, g3, b3, ident, t);
    if (t < 128) sb[t] = 0.f;
    __syncthreads();
    for (int i = t; i < 2048; i += 256){
        int r = i >> 5, u = i & 31;
        ((uint*)(As + r * 72))[u] = ((const uint*)(o + (size_t)row0 * 64))[i];
        ((uint*)(Ws + r * 72))[u] = ((const uint*)Wo)[i];
    }
    __syncthreads();
    int w = t >> 6, l = t & 63, m = l & 15, q4 = l >> 4;
    const ushort* ap = As + (16 * w + m) * 72 + q4 * 8;
    short8 a0 = ldf(ap), a1 = ldf(ap + 32);
    #pragma unroll
    for (int nt = 0; nt < 4; ++nt){
        const ushort* bp = Ws + (nt * 16 + m) * 72 + q4 * 8;
        floatx4 c = {0.f, 0.f, 0.f, 0.f};
        c = mfma16(a0, ldf(bp), c);
        c = mfma16(a1, ldf(bp + 32), c);
        int ch = nt * 16 + m;
        float bv = bf2f(bo[ch]);
        float ba = sf[ch], bb = sf[64 + ch];
        float vs = 0.f, vss = 0.f;
        #pragma unroll
        for (int r = 0; r < 4; ++r){
            size_t gi = (size_t)(row0 + 16 * w + q4 * 4 + r) * 64 + ch;
            float val = c[r] + bv + ba * bf2f(h[gi]) + bb;
            o[gi] = f2bf(val);
            vs += val; vss += val * val;
        }
        vs  += __shfl_xor(vs, 16, 64);  vs  += __shfl_xor(vs, 32, 64);
        vss += __shfl_xor(vss, 16, 64); vss += __shfl_xor(vss, 32, 64);
        if (q4 == 0){
            atomicAdd(&sb[ch], vs);
            atomicAdd(&sb[64 + ch], vss);
        }
    }
    __syncthreads();
    if (t < 64){
        atomicAdd(&stats[t], sb[t]);
        atomicAdd(&stats[64 + t], sb[64 + t]);
    }
}

// ---------------- comb: outb = bn1(hl)+bn2(ha); hout = outb + MLP(outb); BN3 stats ----------------
__global__ void comb_k(const ushort* __restrict__ hlpre, const ushort* __restrict__ hapre,
                       const float* __restrict__ st1, const ushort* __restrict__ n1g,
                       const ushort* __restrict__ n1b,
                       const float* __restrict__ st2, const ushort* __restrict__ n2g,
                       const ushort* __restrict__ n2b,
                       const ushort* __restrict__ W1, const ushort* __restrict__ b1,
                       const ushort* __restrict__ W2, const ushort* __restrict__ b2,
                       ushort* __restrict__ hout, float* __restrict__ stats){
    __shared__ __align__(16) ushort Ob[64 * 72];
    __shared__ float Of[64 * 64];
    __shared__ __align__(16) ushort W1s[128 * 72];
    __shared__ __align__(16) ushort Hs[64 * 136];
    __shared__ __align__(16) ushort W2s[64 * 136];
    __shared__ float sb[128];
    __shared__ float sf1[128], sf2[128];
    int t = threadIdx.x;
    int row0 = blockIdx.x * 64;
    if (t < 128){
        const float* st = (t < 64) ? st1 : st2;
        const ushort* g = (t < 64) ? n1g : n2g;
        const ushort* b = (t < 64) ? n1b : n2b;
        float* f = (t < 64) ? sf1 : sf2;
        int c = t & 63;
        float mu  = st[c] * (1.f / NTOT);
        float var = st[64 + c] * (1.f / NTOT) - mu * mu;
        float a = rsqrtf(var + EPSV) * bf2f(g[c]);
        f[c] = a;
        f[64 + c] = bf2f(b[c]) - mu * a;
        sb[t] = 0.f;
    }
    __syncthreads();
    for (int i = t; i < 2048; i += 256){
        int r = i >> 5, u = i & 31;
        size_t gi = (size_t)(row0 + r) * 32 + u;
        uint wl = ((const uint*)hlpre)[gi], wa = ((const uint*)hapre)[gi];
        int c0 = u * 2;
        float2 pl = bfp2(wl), pa = bfp2(wa);
        float v0 = pl.x * sf1[c0] + sf1[64 + c0] + pa.x * sf2[c0] + sf2[64 + c0];
        float v1 = pl.y * sf1[c0 + 1] + sf1[64 + c0 + 1] + pa.y * sf2[c0 + 1] + sf2[64 + c0 + 1];
        ((uint*)(Ob + r * 72))[u] = (uint)f2bf(v0) | ((uint)f2bf(v1) << 16);
        Of[r * 64 + c0] = v0; Of[r * 64 + c0 + 1] = v1;
    }
    for (int i = t; i < 4096; i += 256){
        int r = i >> 5, u = i & 31;
        ((uint*)(W1s + r * 72))[u] = ((const uint*)W1)[i];
        int r2 = i >> 6, u2 = i & 63;
        ((uint*)(W2s + r2 * 136))[u2] = ((const uint*)W2)[i];
    }
    __syncthreads();
    int w = t >> 6, l = t & 63, m = l & 15, q4 = l >> 4;
    const ushort* ap = Ob + (16 * w + m) * 72 + q4 * 8;
    short8 a0 = ldf(ap), a1 = ldf(ap + 32);
    #pragma unroll
    for (int nt = 0; nt < 8; ++nt){
        const ushort* bp = W1s + (nt * 16 + m) * 72 + q4 * 8;
        floatx4 c = {0.f, 0.f, 0.f, 0.f};
        c = mfma16(a0, ldf(bp), c);
        c = mfma16(a1, ldf(bp + 32), c);
        float bv = bf2f(b1[nt * 16 + m]);
        #pragma unroll
        for (int r = 0; r < 4; ++r)
            Hs[(16 * w + q4 * 4 + r) * 136 + nt * 16 + m] = f2bf(fmaxf(c[r] + bv, 0.f));
    }
    const ushort* ap2 = Hs + (16 * w + m) * 136 + q4 * 8;
    short8 h0 = ldf(ap2), h1 = ldf(ap2 + 32), h2 = ldf(ap2 + 64), h3 = ldf(ap2 + 96);
    #pragma unroll
    for (int nt = 0; nt < 4; ++nt){
        const ushort* bp = W2s + (nt * 16 + m) * 136 + q4 * 8;
        floatx4 c = {0.f, 0.f, 0.f, 0.f};
        c = mfma16(h0, ldf(bp), c);
        c = mfma16(h1, ldf(bp + 32), c);
        c = mfma16(h2, ldf(bp + 64), c);
        c = mfma16(h3, ldf(bp + 96), c);
        float bv = bf2f(b2[nt * 16 + m]);
        float vs = 0.f, vss = 0.f;
        #pragma unroll
        for (int r = 0; r < 4; ++r){
            int lr = 16 * w + q4 * 4 + r;
            float val = c[r] + bv + Of[lr * 64 + nt * 16 + m];
            hout[(size_t)(row0 + lr) * 64 + nt * 16 + m] = f2bf(val);
            vs += val; vss += val * val;
        }
        vs  += __shfl_xor(vs, 16, 64);  vs  += __shfl_xor(vs, 32, 64);
        vss += __shfl_xor(vss, 16, 64); vss += __shfl_xor(vss, 32, 64);
        if (q4 == 0){
            atomicAdd(&sb[nt * 16 + m], vs);
            atomicAdd(&sb[64 + nt * 16 + m], vss);
        }
    }
    __syncthreads();
    if (t < 64){
        atomicAdd(&stats[t], sb[t]);
        atomicAdd(&stats[64 + t], sb[64 + t]);
    }
}

// ---------------- mean pool (pre-BN h + affine post) + head GEMM ----------------
__global__ void pool_head_k(const ushort* __restrict__ h, const float* __restrict__ st3,
                            const ushort* __restrict__ g3, const ushort* __restrict__ b3,
                            const ushort* __restrict__ Wh, const ushort* __restrict__ bh,
                            const int* __restrict__ flag, void* __restrict__ out){
    __shared__ float red[256];
    __shared__ float pooled[64];
    __shared__ float sf[128];
    int t = threadIdx.x, g = blockIdx.x;
    bnfin(sf, st3, g3, b3, 0, t);
    int c = t & 63, rb = t >> 6;
    float s = 0.f;
    for (int ii = 0; ii < 128; ++ii){
        int r = rb + 4 * ii;
        s += bf2f(h[(size_t)(g * 512 + r) * 64 + c]);
    }
    red[t] = s; __syncthreads();
    if (t < 64)
        pooled[t] = sf[t] * ((red[t] + red[64 + t] + red[128 + t] + red[192 + t]) * (1.f / 512.f))
                  + sf[64 + t];
    __syncthreads();
    if (t < 128){
        float a = bf2f(bh[t]);
        #pragma unroll
        for (int k = 0; k < 64; ++k) a += pooled[k] * bf2f(Wh[t * 64 + k]);
        if (*flag) ((ushort*)out)[(size_t)g * 128 + t] = f2bf(a);
        else       ((float*)out)[(size_t)g * 128 + t] = a;
    }
}

extern "C" void kernel_launch(void* const* d_in, const int* in_sizes, int n_in,
                              void* d_out, int out_size, void* d_ws, size_t ws_size,
                              hipStream_t stream){
    const void* x  = d_in[0];
    const void* pe = d_in[1];
    const int* eidx = (const int*)d_in[2];

    char* ws = (char*)d_ws;
    const size_t MB = 1024 * 1024;
    const size_t KB = 1024;
    ushort* h_buf = (ushort*)(ws);
    ushort* z_buf = (ushort*)(ws + 8 * MB);
    ushort* q_buf = (ushort*)(ws + 16 * MB);
    ushort* k_buf = (ushort*)(ws + 24 * MB);
    ushort* v_buf = (ushort*)(ws + 32 * MB);
    int* csr   = (int*)(ws + 40 * MB);
    int* offs  = (int*)(ws + 44 * MB);
    int* cnt   = (int*)(ws + 44 * MB + 384 * KB);
    int* cur   = (int*)(ws + 44 * MB + 640 * KB);
    float* stats = (float*)(ws + 44 * MB + 896 * KB);
    float* fin   = (float*)(ws + 44 * MB + 904 * KB);
    int*   flag  = (int*)(ws + 44 * MB + 912 * KB);
    ushort* wsa  = (ushort*)(ws + 45 * MB);

    hipMemsetAsync(stats, 0, 13 * 128 * sizeof(float), stream);
    hipMemsetAsync(cnt, 0, 65536 * sizeof(int), stream);

    detect_k<<<1, 64, 0, stream>>>((const uint*)x, flag);

    WPtrs wp;
    for (int i = 0; i < 30; ++i) wp.p[i] = d_in[3 + i];
    convall_k<<<(TOTW + 255) / 256, 256, 0, stream>>>(wp, wsa, flag);

    pe_stats_k<<<256, 256, 0, stream>>>(pe, flag, stats);
    fin_k<<<1, 64, 0, stream>>>(stats, wsa + OG_PEN, wsa + OB_PEN, fin, 16);
    embed_k<<<1024, 256, 0, stream>>>(x, pe, flag, wsa, fin, h_buf);
    hist_k<<<1024, 256, 0, stream>>>(eidx + NEDGE, cnt);
    scan_k<<<1, 1024, 0, stream>>>(cnt, offs, cur);
    scatter_k<<<1024, 256, 0, stream>>>(eidx, eidx + NEDGE, cur, csr);

    for (int l = 0; l < NLAYER; ++l){
        float* st1 = stats + (1 + 3 * l) * 128;
        float* st2 = stats + (2 + 3 * l) * 128;
        float* st3 = stats + (3 + 3 * l) * 128;
        int ident = (l == 0) ? 1 : 0;
        const float* stp = (l == 0) ? stats : stats + (3 * l) * 128;
        const ushort* gp = wsa + ON3G + (l ? (l - 1) : 0) * 64;
        const ushort* bp = wsa + ON3B + (l ? (l - 1) : 0) * 64;

        ginqkv_k<<<1024, 256, 0, stream>>>(h_buf, offs, csr, stp, gp, bp, ident,
                                           wsa + OW_G1 + l * 4096, wsa + OB_G1 + l * 64,
                                           wsa + OW_G2 + l * 4096, wsa + OB_G2 + l * 64,
                                           wsa + OW_Q + l * 4096, wsa + OB_Q + l * 64,
                                           wsa + OW_K + l * 4096, wsa + OB_K + l * 64,
                                           wsa + OW_V + l * 4096, wsa + OB_V + l * 64,
                                           z_buf, q_buf, k_buf, v_buf, st1);
        attn_k<<<512, 256, 0, stream>>>(q_buf, k_buf, v_buf);
        oproj_k<<<1024, 256, 0, stream>>>(q_buf, h_buf, stp, gp, bp, ident,
                                          wsa + OW_O + l * 4096, wsa + OB_O + l * 64, st2);
        comb_k<<<1024, 256, 0, stream>>>(z_buf, q_buf,
                                         st1, wsa + ON1G + l * 64, wsa + ON1B + l * 64,
                                         st2, wsa + ON2G + l * 64, wsa + ON2B + l * 64,
                                         wsa + OW_M1 + l * 8192, wsa + OB_M1 + l * 128,
                                         wsa + OW_M2 + l * 8192, wsa + OB_M2 + l * 64,
                                         h_buf, st3);
    }
    pool_head_k<<<128, 256, 0, stream>>>(h_buf, stats + 12 * 128,
                                         wsa + ON3G + 3 * 64, wsa + ON3B + 3 * 64,
                                         wsa + OW_H, wsa + OB_H, flag, d_out);
}

// Round 12
// 1089.269 us; speedup vs baseline: 1.3941x; 1.3941x over previous
//
#include <hip/hip_runtime.h>

typedef unsigned short ushort;
typedef unsigned int uint;
typedef __attribute__((ext_vector_type(8))) short short8;
typedef __attribute__((ext_vector_type(4))) float floatx4;

#define NTOT   65536
#define CH     64
#define NLAYER 4
#define NEDGE  1048576
#define EPSV   1e-5f

// staged-weight arena element offsets (order = d_in[3..32]); 2-D weights stored TRANSPOSED [n][k]
#define OW_EMB 0
#define OB_EMB 3072
#define OW_PE  3120
#define OB_PE  3376
#define OG_PEN 3392
#define OB_PEN 3408
#define OW_G1  3424
#define OB_G1  19808
#define OW_G2  20064
#define OB_G2  36448
#define OW_Q   36704
#define OB_Q   53088
#define OW_K   53344
#define OB_K   69728
#define OW_V   69984
#define OB_V   86368
#define OW_O   86624
#define OB_O   103008
#define ON1G   103264
#define ON1B   103520
#define ON2G   103776
#define ON2B   104032
#define ON3G   104288
#define ON3B   104544
#define OW_M1  104800
#define OB_M1  137568
#define OW_M2  138080
#define OB_M2  170848
#define OW_H   171104
#define OB_H   179296
#define TOTW   179424

__device__ __forceinline__ float bf2f(ushort u){ return __uint_as_float(((uint)u) << 16); }
__device__ __forceinline__ ushort f2bf(float f){
    uint u = __float_as_uint(f);
    uint r = (u + 0x7fffu + ((u >> 16) & 1u)) >> 16;
    return (ushort)r;
}
__device__ __forceinline__ float2 bfp2(uint w){
    return make_float2(__uint_as_float(w << 16), __uint_as_float(w & 0xffff0000u));
}
__device__ __forceinline__ short8 ldf(const ushort* p){ return *(const short8*)p; }
__device__ __forceinline__ floatx4 mfma16(short8 a, short8 b, floatx4 c){
    return __builtin_amdgcn_mfma_f32_16x16x32_bf16(a, b, c, 0, 0, 0);
}
// compute per-channel BN (a,b) into sf[128]; ident=1 -> identity
__device__ __forceinline__ void bnfin(float* sf, const float* st, const ushort* g,
                                      const ushort* b, int ident, int t){
    if (t < 64){
        float a, bb;
        if (ident){ a = 1.f; bb = 0.f; }
        else {
            float mu  = st[t] * (1.f / NTOT);
            float var = st[64 + t] * (1.f / NTOT) - mu * mu;
            a = rsqrtf(var + EPSV) * bf2f(g[t]);
            bb = bf2f(b[t]) - mu * a;
        }
        sf[t] = a; sf[64 + t] = bb;
    }
}

// ---------------- dtype probe: 1=bf16 inputs, 0=fp32 inputs ----------------
__global__ void detect_k(const uint* __restrict__ x, int* __restrict__ flag){
    int lane = threadIdx.x;
    uint w = x[lane];
    uint e = (w >> 7) & 0xffu;
    int ok = (e >= 100u && e <= 140u) ? 1 : 0;
    unsigned long long m = __ballot(ok);
    if (lane == 0) flag[0] = (__popcll(m) >= 48) ? 1 : 0;
}

// ---------------- convert/copy weights into bf16 arena (2-D weights transposed) ----------------
struct WPtrs { const void* p[30]; };

__global__ void convall_k(WPtrs ptrs, ushort* __restrict__ dst, const int* __restrict__ flag){
    const int offs[31] = {0,3072,3120,3376,3392,3408,3424,19808,20064,36448,36704,
                          53088,53344,69728,69984,86368,86624,103008,103264,103520,
                          103776,104032,104288,104544,104800,137568,138080,170848,
                          171104,179296,179424};
    const int kdt[30] = {64,0,16,0,0,0, 64,0,64,0, 64,0,64,0,64,0,64,0,
                         0,0,0,0,0,0, 64,0,128,0, 64,0};
    const int ndt[30] = {48,0,16,0,0,0, 64,0,64,0, 64,0,64,0,64,0,64,0,
                         0,0,0,0,0,0, 128,0,64,0, 128,0};
    int i = blockIdx.x * blockDim.x + threadIdx.x;
    if (i >= TOTW) return;
    int s = 0;
    while (s < 29 && i >= offs[s + 1]) ++s;
    int j = i - offs[s];
    int srcj = j;
    int K = kdt[s];
    if (K > 0){
        int N = ndt[s], KN = K * N;
        int l = j / KN, r = j - l * KN;
        int n = r / K, k2 = r - n * K;
        srcj = l * KN + k2 * N + n;
    }
    if (*flag) dst[i] = ((const ushort*)ptrs.p[s])[srcj];
    else       dst[i] = f2bf(((const float*)ptrs.p[s])[srcj]);
}

// ---------------- BN stats over pe ----------------
__global__ void pe_stats_k(const void* __restrict__ peraw, const int* __restrict__ flag,
                           float* __restrict__ stats){
    int bf = *flag;
    int t = threadIdx.x;
    int c = t & 15, rb = t >> 4;
    int row0 = blockIdx.x * 256;
    float s = 0.f, ss = 0.f;
    for (int i = 0; i < 16; ++i){
        int r = row0 + rb + 16 * i;
        size_t idx = (size_t)r * 16 + c;
        float v = bf ? bf2f(((const ushort*)peraw)[idx]) : ((const float*)peraw)[idx];
        s += v; ss += v * v;
    }
    __shared__ float red[256];
    red[t] = s; __syncthreads();
    if (t < 16){ float tot = 0.f; for (int j = 0; j < 16; ++j) tot += red[t + 16 * j]; atomicAdd(&stats[t], tot); }
    __syncthreads();
    red[t] = ss; __syncthreads();
    if (t < 16){ float tot = 0.f; for (int j = 0; j < 16; ++j) tot += red[t + 16 * j]; atomicAdd(&stats[64 + t], tot); }
}

__global__ void fin_k(const float* __restrict__ stats, const ushort* __restrict__ g,
                      const ushort* __restrict__ b, float* __restrict__ fin, int nch){
    int c = threadIdx.x;
    if (c >= nch) return;
    float mu  = stats[c] * (1.f / NTOT);
    float var = stats[64 + c] * (1.f / NTOT) - mu * mu;
    float a = rsqrtf(var + EPSV) * bf2f(g[c]);
    fin[c] = a;
    fin[64 + c] = bf2f(b[c]) - mu * a;
}

// ---------------- embedding, MFMA version ----------------
__global__ void embed_k(const void* __restrict__ xraw, const void* __restrict__ peraw,
                        const int* __restrict__ flag, const ushort* __restrict__ wsa,
                        const float* __restrict__ finpe, ushort* __restrict__ hout){
    __shared__ __align__(16) ushort xb[64 * 72];
    __shared__ __align__(16) ushort pen[64 * 24];
    __shared__ __align__(16) ushort Wes[48 * 72];
    __shared__ __align__(16) ushort Wps[16 * 24];
    int bf = *flag;
    int t = threadIdx.x;
    int row0 = blockIdx.x * 64;
    if (bf){
        const uint* xsrc = (const uint*)((const ushort*)xraw + (size_t)row0 * 64);
        for (int i = t; i < 2048; i += 256){
            int r = i >> 5, u = i & 31;
            ((uint*)(xb + r * 72))[u] = xsrc[i];
        }
    } else {
        const float4* xsrc = (const float4*)((const float*)xraw + (size_t)row0 * 64);
        for (int i = t; i < 1024; i += 256){
            int r = i >> 4, u = i & 15;
            float4 f = xsrc[i];
            ((uint*)(xb + r * 72))[2 * u]     = (uint)f2bf(f.x) | ((uint)f2bf(f.y) << 16);
            ((uint*)(xb + r * 72))[2 * u + 1] = (uint)f2bf(f.z) | ((uint)f2bf(f.w) << 16);
        }
    }
    for (int i = t; i < 1024; i += 256){
        int r = i >> 4, k = i & 15;
        size_t idx = (size_t)(row0 + r) * 16 + k;
        float v = bf ? bf2f(((const ushort*)peraw)[idx]) : ((const float*)peraw)[idx];
        pen[r * 24 + k] = f2bf(v * finpe[k] + finpe[64 + k]);
    }
    for (int i = t; i < 1536; i += 256){
        int r = i >> 5, u = i & 31;
        ((uint*)(Wes + r * 72))[u] = ((const uint*)(wsa + OW_EMB))[i];
    }
    {
        int r = t >> 4, k = t & 15;
        Wps[r * 24 + k] = wsa[OW_PE + t];
    }
    __syncthreads();
    int w = t >> 6, l = t & 63, m = l & 15, quad = l >> 4;
    const short8 zero8 = {0, 0, 0, 0, 0, 0, 0, 0};
    const floatx4 zf4 = {0.f, 0.f, 0.f, 0.f};
    const ushort* ap = xb + (16 * w + m) * 72 + quad * 8;
    short8 a0 = ldf(ap), a1 = ldf(ap + 32);
    short8 ape = (quad < 2) ? ldf(pen + (16 * w + m) * 24 + quad * 8) : zero8;
    #pragma unroll
    for (int nt = 0; nt < 4; ++nt){
        floatx4 c = zf4;
        float bias;
        if (nt < 3){
            const ushort* bp = Wes + (nt * 16 + m) * 72 + quad * 8;
            c = mfma16(a0, ldf(bp), c);
            c = mfma16(a1, ldf(bp + 32), c);
            bias = bf2f(wsa[OB_EMB + nt * 16 + m]);
        } else {
            short8 bpe = (quad < 2) ? ldf(Wps + m * 24 + quad * 8) : zero8;
            c = mfma16(ape, bpe, c);
            bias = bf2f(wsa[OB_PE + m]);
        }
        #pragma unroll
        for (int r = 0; r < 4; ++r)
            hout[(size_t)(row0 + 16 * w + quad * 4 + r) * 64 + nt * 16 + m] = f2bf(c[r] + bias);
    }
}

// ---------------- CSR build: hist -> scan -> scatter ----------------
__global__ void hist_k(const int* __restrict__ dst, int* __restrict__ cnt){
    int stride = gridDim.x * blockDim.x;
    for (int e = blockIdx.x * blockDim.x + threadIdx.x; e < NEDGE; e += stride)
        atomicAdd(&cnt[dst[e]], 1);
}

__global__ void scan_k(const int* __restrict__ cnt, int* __restrict__ offs, int* __restrict__ cur){
    int t = threadIdx.x;
    int base0 = t * 64;
    int s = 0;
    for (int i = 0; i < 64; ++i) s += cnt[base0 + i];
    __shared__ int pref[1024];
    pref[t] = s; __syncthreads();
    for (int off = 1; off < 1024; off <<= 1){
        int v = (t >= off) ? pref[t - off] : 0;
        __syncthreads();
        pref[t] += v;
        __syncthreads();
    }
    int run = pref[t] - s;
    for (int i = 0; i < 64; ++i){
        offs[base0 + i] = run;
        cur[base0 + i]  = run;
        run += cnt[base0 + i];
    }
    if (t == 1023) offs[65536] = run;
}

__global__ void scatter_k(const int* __restrict__ src, const int* __restrict__ dst,
                          int* __restrict__ cur, int* __restrict__ csr){
    int stride = gridDim.x * blockDim.x;
    for (int e = blockIdx.x * blockDim.x + threadIdx.x; e < NEDGE; e += stride){
        int p = atomicAdd(&cur[dst[e]], 1);
        csr[p] = src[e];
    }
}

// ---------------- GIN aggregate with BN-on-read (high-occupancy, separate) ----------------
__global__ void agg_k(const ushort* __restrict__ h, const int* __restrict__ offs,
                      const int* __restrict__ csr, ushort* __restrict__ z,
                      const float* __restrict__ st, const ushort* __restrict__ g,
                      const ushort* __restrict__ b, int ident){
    __shared__ float sf[128];
    int t = threadIdx.x;
    bnfin(sf, st, g, b, ident, t);
    __syncthreads();
    int w = t >> 6, l = t & 63;
    int node = blockIdx.x * 8 + w * 2 + (l >> 5);
    int c2 = l & 31;
    const uint* hp = (const uint*)h;
    int beg = offs[node], end = offs[node + 1];
    float2 s = bfp2(hp[(size_t)node * 32 + c2]);
    for (int i = beg; i < end; ++i){
        int sn = csr[i];
        float2 p = bfp2(hp[(size_t)sn * 32 + c2]);
        s.x += p.x; s.y += p.y;
    }
    float n = (float)(1 + end - beg);
    int c0 = c2 * 2;
    float o0 = sf[c0] * s.x + n * sf[64 + c0];
    float o1 = sf[c0 + 1] * s.y + n * sf[64 + c0 + 1];
    ((uint*)z)[(size_t)node * 32 + c2] = (uint)f2bf(o0) | ((uint)f2bf(o1) << 16);
}

// ======== fused GIN-MLP + QKV, tile-paired: 512 blocks × 2 row-tiles, weights staged once ========
__global__ void ginqkv_k(const ushort* __restrict__ z, const ushort* __restrict__ h,
                         const float* __restrict__ st3, const ushort* __restrict__ g3,
                         const ushort* __restrict__ b3, int ident,
                         const ushort* __restrict__ W1, const ushort* __restrict__ b1,
                         const ushort* __restrict__ W2, const ushort* __restrict__ b2,
                         const ushort* __restrict__ Wq, const ushort* __restrict__ bq,
                         const ushort* __restrict__ Wk, const ushort* __restrict__ bk,
                         const ushort* __restrict__ Wv, const ushort* __restrict__ bv,
                         ushort* __restrict__ zout, ushort* __restrict__ qo,
                         ushort* __restrict__ ko, ushort* __restrict__ vo,
                         float* __restrict__ stats){
    __shared__ __align__(16) ushort As[64 * 72];
    __shared__ __align__(16) ushort Hs[64 * 72];
    __shared__ __align__(16) ushort W1s[64 * 72];
    __shared__ __align__(16) ushort W2s[64 * 72];
    __shared__ __align__(16) ushort Wqs[64 * 72];
    __shared__ __align__(16) ushort Wks[64 * 72];
    __shared__ __align__(16) ushort Wvs[64 * 72];
    __shared__ float sb[128];
    __shared__ float sf[128];
    int t = threadIdx.x;
    bnfin(sf, st3, g3, b3, ident, t);
    if (t < 128) sb[t] = 0.f;
    for (int i = t; i < 2048; i += 256){
        int r = i >> 5, u = i & 31;
        ((uint*)(W1s + r * 72))[u] = ((const uint*)W1)[i];
        ((uint*)(W2s + r * 72))[u] = ((const uint*)W2)[i];
        ((uint*)(Wqs + r * 72))[u] = ((const uint*)Wq)[i];
        ((uint*)(Wks + r * 72))[u] = ((const uint*)Wk)[i];
        ((uint*)(Wvs + r * 72))[u] = ((const uint*)Wv)[i];
    }
    __syncthreads();
    int w = t >> 6, l = t & 63, m = l & 15, q4 = l >> 4;
    ushort* outs[3] = {qo, ko, vo};
    const ushort* bias[3] = {bq, bk, bv};
    const ushort* wmats[3] = {Wqs, Wks, Wvs};

    for (int tile = 0; tile < 2; ++tile){
        int row0 = blockIdx.x * 128 + tile * 64;
        if (tile) __syncthreads();   // previous tile's LDS reads complete
        for (int i = t; i < 2048; i += 256){
            int r = i >> 5, u = i & 31;
            ((uint*)(As + r * 72))[u] = ((const uint*)(z + (size_t)row0 * 64))[i];
            uint hv = ((const uint*)(h + (size_t)row0 * 64))[i];
            int c0 = u * 2;
            float2 p = bfp2(hv);
            ((uint*)(Hs + r * 72))[u] = (uint)f2bf(p.x * sf[c0] + sf[64 + c0])
                                      | ((uint)f2bf(p.y * sf[c0 + 1] + sf[64 + c0 + 1]) << 16);
        }
        __syncthreads();
        const ushort* ap = As + (16 * w + m) * 72 + q4 * 8;
        short8 a0 = ldf(ap), a1 = ldf(ap + 32);
        const ushort* hpp = Hs + (16 * w + m) * 72 + q4 * 8;
        short8 h0 = ldf(hpp), h1 = ldf(hpp + 32);
        floatx4 acc[4];
        #pragma unroll
        for (int nt = 0; nt < 4; ++nt){
            const ushort* bp = W1s + (nt * 16 + m) * 72 + q4 * 8;
            floatx4 c = {0.f, 0.f, 0.f, 0.f};
            c = mfma16(a0, ldf(bp), c);
            c = mfma16(a1, ldf(bp + 32), c);
            acc[nt] = c;
        }
        #pragma unroll
        for (int nt = 0; nt < 4; ++nt){
            float bv = bf2f(b1[nt * 16 + m]);
            #pragma unroll
            for (int r = 0; r < 4; ++r)
                As[(16 * w + q4 * 4 + r) * 72 + nt * 16 + m] = f2bf(fmaxf(acc[nt][r] + bv, 0.f));
        }
        const ushort* ap2 = As + (16 * w + m) * 72 + q4 * 8;
        short8 t0 = ldf(ap2), t1 = ldf(ap2 + 32);
        #pragma unroll
        for (int nt = 0; nt < 4; ++nt){
            const ushort* bp = W2s + (nt * 16 + m) * 72 + q4 * 8;
            floatx4 c = {0.f, 0.f, 0.f, 0.f};
            c = mfma16(t0, ldf(bp), c);
            c = mfma16(t1, ldf(bp + 32), c);
            float bv = bf2f(b2[nt * 16 + m]);
            float vs = 0.f, vss = 0.f;
            #pragma unroll
            for (int r = 0; r < 4; ++r){
                int lr = 16 * w + q4 * 4 + r;
                float val = c[r] + bv + bf2f(Hs[lr * 72 + nt * 16 + m]);
                zout[(size_t)(row0 + lr) * 64 + nt * 16 + m] = f2bf(val);
                vs += val; vss += val * val;
            }
            vs  += __shfl_xor(vs, 16, 64);  vs  += __shfl_xor(vs, 32, 64);
            vss += __shfl_xor(vss, 16, 64); vss += __shfl_xor(vss, 32, 64);
            if (q4 == 0){
                atomicAdd(&sb[nt * 16 + m], vs);
                atomicAdd(&sb[64 + nt * 16 + m], vss);
            }
        }
        #pragma unroll
        for (int o = 0; o < 3; ++o){
            #pragma unroll
            for (int nt = 0; nt < 4; ++nt){
                const ushort* bp = wmats[o] + (nt * 16 + m) * 72 + q4 * 8;
                floatx4 c = {0.f, 0.f, 0.f, 0.f};
                c = mfma16(h0, ldf(bp), c);
                c = mfma16(h1, ldf(bp + 32), c);
                float bv2 = bf2f(bias[o][nt * 16 + m]);
                #pragma unroll
                for (int r = 0; r < 4; ++r)
                    outs[o][(size_t)(row0 + 16 * w + q4 * 4 + r) * 64 + nt * 16 + m] = f2bf(c[r] + bv2);
            }
        }
    }
    __syncthreads();
    if (t < 64){
        atomicAdd(&stats[t], sb[t]);
        atomicAdd(&stats[64 + t], sb[64 + t]);
    }
}

// ---------------- MFMA flash attention, shift-free softmax ----------------
__global__ void attn_k(ushort* __restrict__ q, const ushort* __restrict__ k,
                       const ushort* __restrict__ v){
    __shared__ __align__(16) ushort Ks[512 * 24];
    __shared__ __align__(16) ushort Vt[16 * 536];
    int t = threadIdx.x;
    int g = blockIdx.x >> 2, head = blockIdx.x & 3;
    int base = g * 512;
    for (int i = t; i < 4096; i += 256){
        int n = i >> 3, u = i & 7;
        uint kw = ((const uint*)(k + (size_t)(base + n) * 64 + head * 16))[u];
        uint vw = ((const uint*)(v + (size_t)(base + n) * 64 + head * 16))[u];
        float2 kf = bfp2(kw);
        Ks[n * 24 + 2 * u]     = f2bf(kf.x * 0.25f);
        Ks[n * 24 + 2 * u + 1] = f2bf(kf.y * 0.25f);
        Vt[(2 * u) * 536 + n]     = (ushort)(vw & 0xffffu);
        Vt[(2 * u + 1) * 536 + n] = (ushort)(vw >> 16);
    }
    __syncthreads();
    int w = t >> 6, l = t & 63, m16 = l & 15, quad = l >> 4;
    const short8 zero8 = {0, 0, 0, 0, 0, 0, 0, 0};
    const floatx4 zf4 = {0.f, 0.f, 0.f, 0.f};
    int key1 = ((m16 >> 2) << 3) + (m16 & 3);

    for (int qi = 0; qi < 8; ++qi){
        int qt = w * 8 + qi;
        int qrow = base + qt * 16 + m16;
        short8 qf = zero8;
        if (quad < 2) qf = ldf(q + (size_t)qrow * 64 + head * 16 + quad * 8);
        floatx4 O = zf4;
        float ll = 0.f;
        for (int kg = 0; kg < 16; ++kg){
            int kb = kg * 32;
            short8 af1 = zero8, af2 = zero8;
            if (quad < 2){
                const ushort* kp = Ks + (kb + key1) * 24 + quad * 8;
                af1 = ldf(kp);
                af2 = ldf(kp + 96);
            }
            floatx4 s1 = mfma16(af1, qf, zf4);
            floatx4 s2 = mfma16(af2, qf, zf4);
            float p0 = __expf(fminf(s1[0], 50.f)), p1 = __expf(fminf(s1[1], 50.f));
            float p2 = __expf(fminf(s1[2], 50.f)), p3 = __expf(fminf(s1[3], 50.f));
            float p4 = __expf(fminf(s2[0], 50.f)), p5 = __expf(fminf(s2[1], 50.f));
            float p6 = __expf(fminf(s2[2], 50.f)), p7 = __expf(fminf(s2[3], 50.f));
            ll += ((p0 + p1) + (p2 + p3)) + ((p4 + p5) + (p6 + p7));
            short8 pf;
            pf[0] = (short)f2bf(p0); pf[1] = (short)f2bf(p1);
            pf[2] = (short)f2bf(p2); pf[3] = (short)f2bf(p3);
            pf[4] = (short)f2bf(p4); pf[5] = (short)f2bf(p5);
            pf[6] = (short)f2bf(p6); pf[7] = (short)f2bf(p7);
            short8 vf = ldf(Vt + m16 * 536 + kb + quad * 8);
            O = mfma16(vf, pf, O);
        }
        ll += __shfl_xor(ll, 16, 64);
        ll += __shfl_xor(ll, 32, 64);
        float inv = 1.f / ll;
        uint lo = (uint)f2bf(O[0] * inv) | ((uint)f2bf(O[1] * inv) << 16);
        uint hi = (uint)f2bf(O[2] * inv) | ((uint)f2bf(O[3] * inv) << 16);
        uint2 st = {lo, hi};
        *(uint2*)(q + (size_t)qrow * 64 + head * 16 + quad * 4) = st;
    }
}

// ---------------- O-projection + bn(h) residual + BN2 stats, tile-paired ----------------
__global__ void oproj_k(ushort* __restrict__ o, const ushort* __restrict__ h,
                        const float* __restrict__ st3, const ushort* __restrict__ g3,
                        const ushort* __restrict__ b3, int ident,
                        const ushort* __restrict__ Wo, const ushort* __restrict__ bo,
                        float* __restrict__ stats){
    __shared__ __align__(16) ushort As[64 * 72];
    __shared__ __align__(16) ushort Ws[64 * 72];
    __shared__ float sb[128];
    __shared__ float sf[128];
    int t = threadIdx.x;
    bnfin(sf, st3, g3, b3, ident, t);
    if (t < 128) sb[t] = 0.f;
    for (int i = t; i < 2048; i += 256){
        int r = i >> 5, u = i & 31;
        ((uint*)(Ws + r * 72))[u] = ((const uint*)Wo)[i];
    }
    __syncthreads();
    int w = t >> 6, l = t & 63, m = l & 15, q4 = l >> 4;
    for (int tile = 0; tile < 2; ++tile){
        int row0 = blockIdx.x * 128 + tile * 64;
        if (tile) __syncthreads();
        for (int i = t; i < 2048; i += 256){
            int r = i >> 5, u = i & 31;
            ((uint*)(As + r * 72))[u] = ((const uint*)(o + (size_t)row0 * 64))[i];
        }
        __syncthreads();
        const ushort* ap = As + (16 * w + m) * 72 + q4 * 8;
        short8 a0 = ldf(ap), a1 = ldf(ap + 32);
        #pragma unroll
        for (int nt = 0; nt < 4; ++nt){
            const ushort* bp = Ws + (nt * 16 + m) * 72 + q4 * 8;
            floatx4 c = {0.f, 0.f, 0.f, 0.f};
            c = mfma16(a0, ldf(bp), c);
            c = mfma16(a1, ldf(bp + 32), c);
            int ch = nt * 16 + m;
            float bv = bf2f(bo[ch]);
            float ba = sf[ch], bb = sf[64 + ch];
            float vs = 0.f, vss = 0.f;
            #pragma unroll
            for (int r = 0; r < 4; ++r){
                size_t gi = (size_t)(row0 + 16 * w + q4 * 4 + r) * 64 + ch;
                float val = c[r] + bv + ba * bf2f(h[gi]) + bb;
                o[gi] = f2bf(val);
                vs += val; vss += val * val;
            }
            vs  += __shfl_xor(vs, 16, 64);  vs  += __shfl_xor(vs, 32, 64);
            vss += __shfl_xor(vss, 16, 64); vss += __shfl_xor(vss, 32, 64);
            if (q4 == 0){
                atomicAdd(&sb[ch], vs);
                atomicAdd(&sb[64 + ch], vss);
            }
        }
    }
    __syncthreads();
    if (t < 64){
        atomicAdd(&stats[t], sb[t]);
        atomicAdd(&stats[64 + t], sb[64 + t]);
    }
}

// ---------------- comb, tile-paired: weights staged once ----------------
__global__ void comb_k(const ushort* __restrict__ hlpre, const ushort* __restrict__ hapre,
                       const float* __restrict__ st1, const ushort* __restrict__ n1g,
                       const ushort* __restrict__ n1b,
                       const float* __restrict__ st2, const ushort* __restrict__ n2g,
                       const ushort* __restrict__ n2b,
                       const ushort* __restrict__ W1, const ushort* __restrict__ b1,
                       const ushort* __restrict__ W2, const ushort* __restrict__ b2,
                       ushort* __restrict__ hout, float* __restrict__ stats){
    __shared__ __align__(16) ushort Ob[64 * 72];
    __shared__ float Of[64 * 64];
    __shared__ __align__(16) ushort W1s[128 * 72];
    __shared__ __align__(16) ushort Hs[64 * 136];
    __shared__ __align__(16) ushort W2s[64 * 136];
    __shared__ float sb[128];
    __shared__ float sf1[128], sf2[128];
    int t = threadIdx.x;
    if (t < 128){
        const float* st = (t < 64) ? st1 : st2;
        const ushort* g = (t < 64) ? n1g : n2g;
        const ushort* b = (t < 64) ? n1b : n2b;
        float* f = (t < 64) ? sf1 : sf2;
        int c = t & 63;
        float mu  = st[c] * (1.f / NTOT);
        float var = st[64 + c] * (1.f / NTOT) - mu * mu;
        float a = rsqrtf(var + EPSV) * bf2f(g[c]);
        f[c] = a;
        f[64 + c] = bf2f(b[c]) - mu * a;
        sb[t] = 0.f;
    }
    for (int i = t; i < 4096; i += 256){
        int r = i >> 5, u = i & 31;
        ((uint*)(W1s + r * 72))[u] = ((const uint*)W1)[i];
        int r2 = i >> 6, u2 = i & 63;
        ((uint*)(W2s + r2 * 136))[u2] = ((const uint*)W2)[i];
    }
    __syncthreads();
    int w = t >> 6, l = t & 63, m = l & 15, q4 = l >> 4;
    for (int tile = 0; tile < 2; ++tile){
        int row0 = blockIdx.x * 128 + tile * 64;
        if (tile) __syncthreads();
        for (int i = t; i < 2048; i += 256){
            int r = i >> 5, u = i & 31;
            size_t gi = (size_t)(row0 + r) * 32 + u;
            uint wl = ((const uint*)hlpre)[gi], wa = ((const uint*)hapre)[gi];
            int c0 = u * 2;
            float2 pl = bfp2(wl), pa = bfp2(wa);
            float v0 = pl.x * sf1[c0] + sf1[64 + c0] + pa.x * sf2[c0] + sf2[64 + c0];
            float v1 = pl.y * sf1[c0 + 1] + sf1[64 + c0 + 1] + pa.y * sf2[c0 + 1] + sf2[64 + c0 + 1];
            ((uint*)(Ob + r * 72))[u] = (uint)f2bf(v0) | ((uint)f2bf(v1) << 16);
            Of[r * 64 + c0] = v0; Of[r * 64 + c0 + 1] = v1;
        }
        __syncthreads();
        const ushort* ap = Ob + (16 * w + m) * 72 + q4 * 8;
        short8 a0 = ldf(ap), a1 = ldf(ap + 32);
        #pragma unroll
        for (int nt = 0; nt < 8; ++nt){
            const ushort* bp = W1s + (nt * 16 + m) * 72 + q4 * 8;
            floatx4 c = {0.f, 0.f, 0.f, 0.f};
            c = mfma16(a0, ldf(bp), c);
            c = mfma16(a1, ldf(bp + 32), c);
            float bv = bf2f(b1[nt * 16 + m]);
            #pragma unroll
            for (int r = 0; r < 4; ++r)
                Hs[(16 * w + q4 * 4 + r) * 136 + nt * 16 + m] = f2bf(fmaxf(c[r] + bv, 0.f));
        }
        const ushort* ap2 = Hs + (16 * w + m) * 136 + q4 * 8;
        short8 h0 = ldf(ap2), h1 = ldf(ap2 + 32), h2 = ldf(ap2 + 64), h3 = ldf(ap2 + 96);
        #pragma unroll
        for (int nt = 0; nt < 4; ++nt){
            const ushort* bp = W2s + (nt * 16 + m) * 136 + q4 * 8;
            floatx4 c = {0.f, 0.f, 0.f, 0.f};
            c = mfma16(h0, ldf(bp), c);
            c = mfma16(h1, ldf(bp + 32), c);
            c = mfma16(h2, ldf(bp + 64), c);
            c = mfma16(h3, ldf(bp + 96), c);
            float bv = bf2f(b2[nt * 16 + m]);
            float vs = 0.f, vss = 0.f;
            #pragma unroll
            for (int r = 0; r < 4; ++r){
                int lr = 16 * w + q4 * 4 + r;
                float val = c[r] + bv + Of[lr * 64 + nt * 16 + m];
                hout[(size_t)(row0 + lr) * 64 + nt * 16 + m] = f2bf(val);
                vs += val; vss += val * val;
            }
            vs  += __shfl_xor(vs, 16, 64);  vs  += __shfl_xor(vs, 32, 64);
            vss += __shfl_xor(vss, 16, 64); vss += __shfl_xor(vss, 32, 64);
            if (q4 == 0){
                atomicAdd(&sb[nt * 16 + m], vs);
                atomicAdd(&sb[64 + nt * 16 + m], vss);
            }
        }
    }
    __syncthreads();
    if (t < 64){
        atomicAdd(&stats[t], sb[t]);
        atomicAdd(&stats[64 + t], sb[64 + t]);
    }
}

// ---------------- mean pool (pre-BN h + affine post) + head GEMM ----------------
__global__ void pool_head_k(const ushort* __restrict__ h, const float* __restrict__ st3,
                            const ushort* __restrict__ g3, const ushort* __restrict__ b3,
                            const ushort* __restrict__ Wh, const ushort* __restrict__ bh,
                            const int* __restrict__ flag, void* __restrict__ out){
    __shared__ float red[256];
    __shared__ float pooled[64];
    __shared__ float sf[128];
    int t = threadIdx.x, g = blockIdx.x;
    bnfin(sf, st3, g3, b3, 0, t);
    int c = t & 63, rb = t >> 6;
    float s = 0.f;
    for (int ii = 0; ii < 128; ++ii){
        int r = rb + 4 * ii;
        s += bf2f(h[(size_t)(g * 512 + r) * 64 + c]);
    }
    red[t] = s; __syncthreads();
    if (t < 64)
        pooled[t] = sf[t] * ((red[t] + red[64 + t] + red[128 + t] + red[192 + t]) * (1.f / 512.f))
                  + sf[64 + t];
    __syncthreads();
    if (t < 128){
        float a = bf2f(bh[t]);
        #pragma unroll
        for (int k = 0; k < 64; ++k) a += pooled[k] * bf2f(Wh[t * 64 + k]);
        if (*flag) ((ushort*)out)[(size_t)g * 128 + t] = f2bf(a);
        else       ((float*)out)[(size_t)g * 128 + t] = a;
    }
}

extern "C" void kernel_launch(void* const* d_in, const int* in_sizes, int n_in,
                              void* d_out, int out_size, void* d_ws, size_t ws_size,
                              hipStream_t stream){
    const void* x  = d_in[0];
    const void* pe = d_in[1];
    const int* eidx = (const int*)d_in[2];

    char* ws = (char*)d_ws;
    const size_t MB = 1024 * 1024;
    const size_t KB = 1024;
    ushort* h_buf = (ushort*)(ws);
    ushort* z_buf = (ushort*)(ws + 8 * MB);
    ushort* q_buf = (ushort*)(ws + 16 * MB);
    ushort* k_buf = (ushort*)(ws + 24 * MB);
    ushort* v_buf = (ushort*)(ws + 32 * MB);
    int* csr   = (int*)(ws + 40 * MB);
    int* offs  = (int*)(ws + 44 * MB);
    int* cnt   = (int*)(ws + 44 * MB + 384 * KB);
    int* cur   = (int*)(ws + 44 * MB + 640 * KB);
    float* stats = (float*)(ws + 44 * MB + 896 * KB);
    float* fin   = (float*)(ws + 44 * MB + 904 * KB);
    int*   flag  = (int*)(ws + 44 * MB + 912 * KB);
    ushort* wsa  = (ushort*)(ws + 45 * MB);

    hipMemsetAsync(stats, 0, 13 * 128 * sizeof(float), stream);
    hipMemsetAsync(cnt, 0, 65536 * sizeof(int), stream);

    detect_k<<<1, 64, 0, stream>>>((const uint*)x, flag);

    WPtrs wp;
    for (int i = 0; i < 30; ++i) wp.p[i] = d_in[3 + i];
    convall_k<<<(TOTW + 255) / 256, 256, 0, stream>>>(wp, wsa, flag);

    pe_stats_k<<<256, 256, 0, stream>>>(pe, flag, stats);
    fin_k<<<1, 64, 0, stream>>>(stats, wsa + OG_PEN, wsa + OB_PEN, fin, 16);
    embed_k<<<1024, 256, 0, stream>>>(x, pe, flag, wsa, fin, h_buf);
    hist_k<<<1024, 256, 0, stream>>>(eidx + NEDGE, cnt);
    scan_k<<<1, 1024, 0, stream>>>(cnt, offs, cur);
    scatter_k<<<1024, 256, 0, stream>>>(eidx, eidx + NEDGE, cur, csr);

    for (int l = 0; l < NLAYER; ++l){
        float* st1 = stats + (1 + 3 * l) * 128;
        float* st2 = stats + (2 + 3 * l) * 128;
        float* st3 = stats + (3 + 3 * l) * 128;
        int ident = (l == 0) ? 1 : 0;
        const float* stp = (l == 0) ? stats : stats + (3 * l) * 128;
        const ushort* gp = wsa + ON3G + (l ? (l - 1) : 0) * 64;
        const ushort* bp = wsa + ON3B + (l ? (l - 1) : 0) * 64;

        agg_k<<<8192, 256, 0, stream>>>(h_buf, offs, csr, z_buf, stp, gp, bp, ident);
        ginqkv_k<<<512, 256, 0, stream>>>(z_buf, h_buf, stp, gp, bp, ident,
                                          wsa + OW_G1 + l * 4096, wsa + OB_G1 + l * 64,
                                          wsa + OW_G2 + l * 4096, wsa + OB_G2 + l * 64,
                                          wsa + OW_Q + l * 4096, wsa + OB_Q + l * 64,
                                          wsa + OW_K + l * 4096, wsa + OB_K + l * 64,
                                          wsa + OW_V + l * 4096, wsa + OB_V + l * 64,
                                          z_buf, q_buf, k_buf, v_buf, st1);
        attn_k<<<512, 256, 0, stream>>>(q_buf, k_buf, v_buf);
        oproj_k<<<512, 256, 0, stream>>>(q_buf, h_buf, stp, gp, bp, ident,
                                         wsa + OW_O + l * 4096, wsa + OB_O + l * 64, st2);
        comb_k<<<512, 256, 0, stream>>>(z_buf, q_buf,
                                        st1, wsa + ON1G + l * 64, wsa + ON1B + l * 64,
                                        st2, wsa + ON2G + l * 64, wsa + ON2B + l * 64,
                                        wsa + OW_M1 + l * 8192, wsa + OB_M1 + l * 128,
                                        wsa + OW_M2 + l * 8192, wsa + OB_M2 + l * 64,
                                        h_buf, st3);
    }
    pool_head_k<<<128, 256, 0, stream>>>(h_buf, stats + 12 * 128,
                                         wsa + ON3G + 3 * 64, wsa + ON3B + 3 * 64,
                                         wsa + OW_H, wsa + OB_H, flag, d_out);
}

// Round 13
// 1064.210 us; speedup vs baseline: 1.4269x; 1.0235x over previous
//
#include <hip/hip_runtime.h>

typedef unsigned short ushort;
typedef unsigned int uint;
typedef __attribute__((ext_vector_type(8))) short short8;
typedef __attribute__((ext_vector_type(4))) float floatx4;

#define NTOT   65536
#define CH     64
#define NLAYER 4
#define NEDGE  1048576
#define EPSV   1e-5f

// staged-weight arena element offsets (order = d_in[3..32]); 2-D weights stored TRANSPOSED [n][k]
#define OW_EMB 0
#define OB_EMB 3072
#define OW_PE  3120
#define OB_PE  3376
#define OG_PEN 3392
#define OB_PEN 3408
#define OW_G1  3424
#define OB_G1  19808
#define OW_G2  20064
#define OB_G2  36448
#define OW_Q   36704
#define OB_Q   53088
#define OW_K   53344
#define OB_K   69728
#define OW_V   69984
#define OB_V   86368
#define OW_O   86624
#define OB_O   103008
#define ON1G   103264
#define ON1B   103520
#define ON2G   103776
#define ON2B   104032
#define ON3G   104288
#define ON3B   104544
#define OW_M1  104800
#define OB_M1  137568
#define OW_M2  138080
#define OB_M2  170848
#define OW_H   171104
#define OB_H   179296
#define TOTW   179424

__device__ __forceinline__ float bf2f(ushort u){ return __uint_as_float(((uint)u) << 16); }
__device__ __forceinline__ ushort f2bf(float f){
    uint u = __float_as_uint(f);
    uint r = (u + 0x7fffu + ((u >> 16) & 1u)) >> 16;
    return (ushort)r;
}
__device__ __forceinline__ float2 bfp2(uint w){
    return make_float2(__uint_as_float(w << 16), __uint_as_float(w & 0xffff0000u));
}
__device__ __forceinline__ short8 ldf(const ushort* p){ return *(const short8*)p; }
__device__ __forceinline__ floatx4 mfma16(short8 a, short8 b, floatx4 c){
    return __builtin_amdgcn_mfma_f32_16x16x32_bf16(a, b, c, 0, 0, 0);
}
// compute per-channel BN (a,b) into sf[128]; ident=1 -> identity
__device__ __forceinline__ void bnfin(float* sf, const float* st, const ushort* g,
                                      const ushort* b, int ident, int t){
    if (t < 64){
        float a, bb;
        if (ident){ a = 1.f; bb = 0.f; }
        else {
            float mu  = st[t] * (1.f / NTOT);
            float var = st[64 + t] * (1.f / NTOT) - mu * mu;
            a = rsqrtf(var + EPSV) * bf2f(g[t]);
            bb = bf2f(b[t]) - mu * a;
        }
        sf[t] = a; sf[64 + t] = bb;
    }
}

// ---------------- dtype probe: 1=bf16 inputs, 0=fp32 inputs ----------------
__global__ void detect_k(const uint* __restrict__ x, int* __restrict__ flag){
    int lane = threadIdx.x;
    uint w = x[lane];
    uint e = (w >> 7) & 0xffu;
    int ok = (e >= 100u && e <= 140u) ? 1 : 0;
    unsigned long long m = __ballot(ok);
    if (lane == 0) flag[0] = (__popcll(m) >= 48) ? 1 : 0;
}

// ---------------- convert/copy weights into bf16 arena (2-D weights transposed) ----------------
struct WPtrs { const void* p[30]; };

__global__ void convall_k(WPtrs ptrs, ushort* __restrict__ dst, const int* __restrict__ flag){
    const int offs[31] = {0,3072,3120,3376,3392,3408,3424,19808,20064,36448,36704,
                          53088,53344,69728,69984,86368,86624,103008,103264,103520,
                          103776,104032,104288,104544,104800,137568,138080,170848,
                          171104,179296,179424};
    const int kdt[30] = {64,0,16,0,0,0, 64,0,64,0, 64,0,64,0,64,0,64,0,
                         0,0,0,0,0,0, 64,0,128,0, 64,0};
    const int ndt[30] = {48,0,16,0,0,0, 64,0,64,0, 64,0,64,0,64,0,64,0,
                         0,0,0,0,0,0, 128,0,64,0, 128,0};
    int i = blockIdx.x * blockDim.x + threadIdx.x;
    if (i >= TOTW) return;
    int s = 0;
    while (s < 29 && i >= offs[s + 1]) ++s;
    int j = i - offs[s];
    int srcj = j;
    int K = kdt[s];
    if (K > 0){
        int N = ndt[s], KN = K * N;
        int l = j / KN, r = j - l * KN;
        int n = r / K, k2 = r - n * K;
        srcj = l * KN + k2 * N + n;
    }
    if (*flag) dst[i] = ((const ushort*)ptrs.p[s])[srcj];
    else       dst[i] = f2bf(((const float*)ptrs.p[s])[srcj]);
}

// ---------------- BN stats over pe ----------------
__global__ void pe_stats_k(const void* __restrict__ peraw, const int* __restrict__ flag,
                           float* __restrict__ stats){
    int bf = *flag;
    int t = threadIdx.x;
    int c = t & 15, rb = t >> 4;
    int row0 = blockIdx.x * 256;
    float s = 0.f, ss = 0.f;
    for (int i = 0; i < 16; ++i){
        int r = row0 + rb + 16 * i;
        size_t idx = (size_t)r * 16 + c;
        float v = bf ? bf2f(((const ushort*)peraw)[idx]) : ((const float*)peraw)[idx];
        s += v; ss += v * v;
    }
    __shared__ float red[256];
    red[t] = s; __syncthreads();
    if (t < 16){ float tot = 0.f; for (int j = 0; j < 16; ++j) tot += red[t + 16 * j]; atomicAdd(&stats[t], tot); }
    __syncthreads();
    red[t] = ss; __syncthreads();
    if (t < 16){ float tot = 0.f; for (int j = 0; j < 16; ++j) tot += red[t + 16 * j]; atomicAdd(&stats[64 + t], tot); }
}

__global__ void fin_k(const float* __restrict__ stats, const ushort* __restrict__ g,
                      const ushort* __restrict__ b, float* __restrict__ fin, int nch){
    int c = threadIdx.x;
    if (c >= nch) return;
    float mu  = stats[c] * (1.f / NTOT);
    float var = stats[64 + c] * (1.f / NTOT) - mu * mu;
    float a = rsqrtf(var + EPSV) * bf2f(g[c]);
    fin[c] = a;
    fin[64 + c] = bf2f(b[c]) - mu * a;
}

// ---------------- embedding, MFMA version ----------------
__global__ void embed_k(const void* __restrict__ xraw, const void* __restrict__ peraw,
                        const int* __restrict__ flag, const ushort* __restrict__ wsa,
                        const float* __restrict__ finpe, ushort* __restrict__ hout){
    __shared__ __align__(16) ushort xb[64 * 72];
    __shared__ __align__(16) ushort pen[64 * 24];
    __shared__ __align__(16) ushort Wes[48 * 72];
    __shared__ __align__(16) ushort Wps[16 * 24];
    int bf = *flag;
    int t = threadIdx.x;
    int row0 = blockIdx.x * 64;
    if (bf){
        const uint* xsrc = (const uint*)((const ushort*)xraw + (size_t)row0 * 64);
        for (int i = t; i < 2048; i += 256){
            int r = i >> 5, u = i & 31;
            ((uint*)(xb + r * 72))[u] = xsrc[i];
        }
    } else {
        const float4* xsrc = (const float4*)((const float*)xraw + (size_t)row0 * 64);
        for (int i = t; i < 1024; i += 256){
            int r = i >> 4, u = i & 15;
            float4 f = xsrc[i];
            ((uint*)(xb + r * 72))[2 * u]     = (uint)f2bf(f.x) | ((uint)f2bf(f.y) << 16);
            ((uint*)(xb + r * 72))[2 * u + 1] = (uint)f2bf(f.z) | ((uint)f2bf(f.w) << 16);
        }
    }
    for (int i = t; i < 1024; i += 256){
        int r = i >> 4, k = i & 15;
        size_t idx = (size_t)(row0 + r) * 16 + k;
        float v = bf ? bf2f(((const ushort*)peraw)[idx]) : ((const float*)peraw)[idx];
        pen[r * 24 + k] = f2bf(v * finpe[k] + finpe[64 + k]);
    }
    for (int i = t; i < 1536; i += 256){
        int r = i >> 5, u = i & 31;
        ((uint*)(Wes + r * 72))[u] = ((const uint*)(wsa + OW_EMB))[i];
    }
    {
        int r = t >> 4, k = t & 15;
        Wps[r * 24 + k] = wsa[OW_PE + t];
    }
    __syncthreads();
    int w = t >> 6, l = t & 63, m = l & 15, quad = l >> 4;
    const short8 zero8 = {0, 0, 0, 0, 0, 0, 0, 0};
    const floatx4 zf4 = {0.f, 0.f, 0.f, 0.f};
    const ushort* ap = xb + (16 * w + m) * 72 + quad * 8;
    short8 a0 = ldf(ap), a1 = ldf(ap + 32);
    short8 ape = (quad < 2) ? ldf(pen + (16 * w + m) * 24 + quad * 8) : zero8;
    #pragma unroll
    for (int nt = 0; nt < 4; ++nt){
        floatx4 c = zf4;
        float bias;
        if (nt < 3){
            const ushort* bp = Wes + (nt * 16 + m) * 72 + quad * 8;
            c = mfma16(a0, ldf(bp), c);
            c = mfma16(a1, ldf(bp + 32), c);
            bias = bf2f(wsa[OB_EMB + nt * 16 + m]);
        } else {
            short8 bpe = (quad < 2) ? ldf(Wps + m * 24 + quad * 8) : zero8;
            c = mfma16(ape, bpe, c);
            bias = bf2f(wsa[OB_PE + m]);
        }
        #pragma unroll
        for (int r = 0; r < 4; ++r)
            hout[(size_t)(row0 + 16 * w + quad * 4 + r) * 64 + nt * 16 + m] = f2bf(c[r] + bias);
    }
}

// ---------------- CSR build: XCD-partitioned hist -> scan -> XCD-partitioned scatter ----------
// Cross-XCD L2s are non-coherent: a csr/cnt line touched from multiple XCDs bounces
// through HBM each time (measured 72 MB writes for 4 MB payload). Partition by dst
// range so each line is touched by one XCD only (blockIdx&7 ~ XCD round-robin heuristic;
// correctness is mapping-independent). Cost: 8x edge re-read (~64 MB, ~11 us).
__global__ void hist_k(const int* __restrict__ dst, int* __restrict__ cnt){
    int xcd = blockIdx.x & 7;
    int slice = blockIdx.x >> 3;            // 128 slices x 8192 edges
    int lo = xcd << 13, hi = lo + 8192;
    int e0 = slice * 8192;
    for (int i = threadIdx.x; i < 8192; i += 256){
        int dv = dst[e0 + i];
        if (dv >= lo && dv < hi) atomicAdd(&cnt[dv], 1);
    }
}

__global__ void scan_k(const int* __restrict__ cnt, int* __restrict__ offs, int* __restrict__ cur){
    int t = threadIdx.x;
    int base0 = t * 64;
    int s = 0;
    for (int i = 0; i < 64; ++i) s += cnt[base0 + i];
    __shared__ int pref[1024];
    pref[t] = s; __syncthreads();
    for (int off = 1; off < 1024; off <<= 1){
        int v = (t >= off) ? pref[t - off] : 0;
        __syncthreads();
        pref[t] += v;
        __syncthreads();
    }
    int run = pref[t] - s;
    for (int i = 0; i < 64; ++i){
        offs[base0 + i] = run;
        cur[base0 + i]  = run;
        run += cnt[base0 + i];
    }
    if (t == 1023) offs[65536] = run;
}

__global__ void scatter_k(const int* __restrict__ src, const int* __restrict__ dst,
                          int* __restrict__ cur, int* __restrict__ csr){
    int xcd = blockIdx.x & 7;
    int slice = blockIdx.x >> 3;
    int lo = xcd << 13, hi = lo + 8192;
    int e0 = slice * 8192;
    for (int i = threadIdx.x; i < 8192; i += 256){
        int e = e0 + i;
        int dv = dst[e];
        if (dv >= lo && dv < hi){
            int p = atomicAdd(&cur[dv], 1);
            csr[p] = src[e];
        }
    }
}

// ---------------- GIN aggregate with BN-on-read (high-occupancy, separate) ----------------
__global__ void agg_k(const ushort* __restrict__ h, const int* __restrict__ offs,
                      const int* __restrict__ csr, ushort* __restrict__ z,
                      const float* __restrict__ st, const ushort* __restrict__ g,
                      const ushort* __restrict__ b, int ident){
    __shared__ float sf[128];
    int t = threadIdx.x;
    bnfin(sf, st, g, b, ident, t);
    __syncthreads();
    int w = t >> 6, l = t & 63;
    int node = blockIdx.x * 8 + w * 2 + (l >> 5);
    int c2 = l & 31;
    const uint* hp = (const uint*)h;
    int beg = offs[node], end = offs[node + 1];
    float2 s = bfp2(hp[(size_t)node * 32 + c2]);
    for (int i = beg; i < end; ++i){
        int sn = csr[i];
        float2 p = bfp2(hp[(size_t)sn * 32 + c2]);
        s.x += p.x; s.y += p.y;
    }
    float n = (float)(1 + end - beg);
    int c0 = c2 * 2;
    float o0 = sf[c0] * s.x + n * sf[64 + c0];
    float o1 = sf[c0 + 1] * s.y + n * sf[64 + c0 + 1];
    ((uint*)z)[(size_t)node * 32 + c2] = (uint)f2bf(o0) | ((uint)f2bf(o1) << 16);
}

// ======== fused GIN-MLP + QKV, tile-paired: 512 blocks × 2 row-tiles, weights staged once ========
__global__ void ginqkv_k(const ushort* __restrict__ z, const ushort* __restrict__ h,
                         const float* __restrict__ st3, const ushort* __restrict__ g3,
                         const ushort* __restrict__ b3, int ident,
                         const ushort* __restrict__ W1, const ushort* __restrict__ b1,
                         const ushort* __restrict__ W2, const ushort* __restrict__ b2,
                         const ushort* __restrict__ Wq, const ushort* __restrict__ bq,
                         const ushort* __restrict__ Wk, const ushort* __restrict__ bk,
                         const ushort* __restrict__ Wv, const ushort* __restrict__ bv,
                         ushort* __restrict__ zout, ushort* __restrict__ qo,
                         ushort* __restrict__ ko, ushort* __restrict__ vo,
                         float* __restrict__ stats){
    __shared__ __align__(16) ushort As[64 * 72];
    __shared__ __align__(16) ushort Hs[64 * 72];
    __shared__ __align__(16) ushort W1s[64 * 72];
    __shared__ __align__(16) ushort W2s[64 * 72];
    __shared__ __align__(16) ushort Wqs[64 * 72];
    __shared__ __align__(16) ushort Wks[64 * 72];
    __shared__ __align__(16) ushort Wvs[64 * 72];
    __shared__ float sb[128];
    __shared__ float sf[128];
    int t = threadIdx.x;
    bnfin(sf, st3, g3, b3, ident, t);
    if (t < 128) sb[t] = 0.f;
    for (int i = t; i < 2048; i += 256){
        int r = i >> 5, u = i & 31;
        ((uint*)(W1s + r * 72))[u] = ((const uint*)W1)[i];
        ((uint*)(W2s + r * 72))[u] = ((const uint*)W2)[i];
        ((uint*)(Wqs + r * 72))[u] = ((const uint*)Wq)[i];
        ((uint*)(Wks + r * 72))[u] = ((const uint*)Wk)[i];
        ((uint*)(Wvs + r * 72))[u] = ((const uint*)Wv)[i];
    }
    __syncthreads();
    int w = t >> 6, l = t & 63, m = l & 15, q4 = l >> 4;
    ushort* outs[3] = {qo, ko, vo};
    const ushort* bias[3] = {bq, bk, bv};
    const ushort* wmats[3] = {Wqs, Wks, Wvs};

    for (int tile = 0; tile < 2; ++tile){
        int row0 = blockIdx.x * 128 + tile * 64;
        if (tile) __syncthreads();   // previous tile's LDS reads complete
        for (int i = t; i < 2048; i += 256){
            int r = i >> 5, u = i & 31;
            ((uint*)(As + r * 72))[u] = ((const uint*)(z + (size_t)row0 * 64))[i];
            uint hv = ((const uint*)(h + (size_t)row0 * 64))[i];
            int c0 = u * 2;
            float2 p = bfp2(hv);
            ((uint*)(Hs + r * 72))[u] = (uint)f2bf(p.x * sf[c0] + sf[64 + c0])
                                      | ((uint)f2bf(p.y * sf[c0 + 1] + sf[64 + c0 + 1]) << 16);
        }
        __syncthreads();
        const ushort* ap = As + (16 * w + m) * 72 + q4 * 8;
        short8 a0 = ldf(ap), a1 = ldf(ap + 32);
        const ushort* hpp = Hs + (16 * w + m) * 72 + q4 * 8;
        short8 h0 = ldf(hpp), h1 = ldf(hpp + 32);
        floatx4 acc[4];
        #pragma unroll
        for (int nt = 0; nt < 4; ++nt){
            const ushort* bp = W1s + (nt * 16 + m) * 72 + q4 * 8;
            floatx4 c = {0.f, 0.f, 0.f, 0.f};
            c = mfma16(a0, ldf(bp), c);
            c = mfma16(a1, ldf(bp + 32), c);
            acc[nt] = c;
        }
        #pragma unroll
        for (int nt = 0; nt < 4; ++nt){
            float bv = bf2f(b1[nt * 16 + m]);
            #pragma unroll
            for (int r = 0; r < 4; ++r)
                As[(16 * w + q4 * 4 + r) * 72 + nt * 16 + m] = f2bf(fmaxf(acc[nt][r] + bv, 0.f));
        }
        const ushort* ap2 = As + (16 * w + m) * 72 + q4 * 8;
        short8 t0 = ldf(ap2), t1 = ldf(ap2 + 32);
        #pragma unroll
        for (int nt = 0; nt < 4; ++nt){
            const ushort* bp = W2s + (nt * 16 + m) * 72 + q4 * 8;
            floatx4 c = {0.f, 0.f, 0.f, 0.f};
            c = mfma16(t0, ldf(bp), c);
            c = mfma16(t1, ldf(bp + 32), c);
            float bv = bf2f(b2[nt * 16 + m]);
            float vs = 0.f, vss = 0.f;
            #pragma unroll
            for (int r = 0; r < 4; ++r){
                int lr = 16 * w + q4 * 4 + r;
                float val = c[r] + bv + bf2f(Hs[lr * 72 + nt * 16 + m]);
                zout[(size_t)(row0 + lr) * 64 + nt * 16 + m] = f2bf(val);
                vs += val; vss += val * val;
            }
            vs  += __shfl_xor(vs, 16, 64);  vs  += __shfl_xor(vs, 32, 64);
            vss += __shfl_xor(vss, 16, 64); vss += __shfl_xor(vss, 32, 64);
            if (q4 == 0){
                atomicAdd(&sb[nt * 16 + m], vs);
                atomicAdd(&sb[64 + nt * 16 + m], vss);
            }
        }
        #pragma unroll
        for (int o = 0; o < 3; ++o){
            #pragma unroll
            for (int nt = 0; nt < 4; ++nt){
                const ushort* bp = wmats[o] + (nt * 16 + m) * 72 + q4 * 8;
                floatx4 c = {0.f, 0.f, 0.f, 0.f};
                c = mfma16(h0, ldf(bp), c);
                c = mfma16(h1, ldf(bp + 32), c);
                float bv2 = bf2f(bias[o][nt * 16 + m]);
                #pragma unroll
                for (int r = 0; r < 4; ++r)
                    outs[o][(size_t)(row0 + 16 * w + q4 * 4 + r) * 64 + nt * 16 + m] = f2bf(c[r] + bv2);
            }
        }
    }
    __syncthreads();
    if (t < 64){
        atomicAdd(&stats[t], sb[t]);
        atomicAdd(&stats[64 + t], sb[64 + t]);
    }
}

// ---------------- MFMA flash attention, shift-free softmax ----------------
__global__ void attn_k(ushort* __restrict__ q, const ushort* __restrict__ k,
                       const ushort* __restrict__ v){
    __shared__ __align__(16) ushort Ks[512 * 24];
    __shared__ __align__(16) ushort Vt[16 * 536];
    int t = threadIdx.x;
    int g = blockIdx.x >> 2, head = blockIdx.x & 3;
    int base = g * 512;
    for (int i = t; i < 4096; i += 256){
        int n = i >> 3, u = i & 7;
        uint kw = ((const uint*)(k + (size_t)(base + n) * 64 + head * 16))[u];
        uint vw = ((const uint*)(v + (size_t)(base + n) * 64 + head * 16))[u];
        float2 kf = bfp2(kw);
        Ks[n * 24 + 2 * u]     = f2bf(kf.x * 0.25f);
        Ks[n * 24 + 2 * u + 1] = f2bf(kf.y * 0.25f);
        Vt[(2 * u) * 536 + n]     = (ushort)(vw & 0xffffu);
        Vt[(2 * u + 1) * 536 + n] = (ushort)(vw >> 16);
    }
    __syncthreads();
    int w = t >> 6, l = t & 63, m16 = l & 15, quad = l >> 4;
    const short8 zero8 = {0, 0, 0, 0, 0, 0, 0, 0};
    const floatx4 zf4 = {0.f, 0.f, 0.f, 0.f};
    int key1 = ((m16 >> 2) << 3) + (m16 & 3);

    for (int qi = 0; qi < 8; ++qi){
        int qt = w * 8 + qi;
        int qrow = base + qt * 16 + m16;
        short8 qf = zero8;
        if (quad < 2) qf = ldf(q + (size_t)qrow * 64 + head * 16 + quad * 8);
        floatx4 O = zf4;
        float ll = 0.f;
        for (int kg = 0; kg < 16; ++kg){
            int kb = kg * 32;
            short8 af1 = zero8, af2 = zero8;
            if (quad < 2){
                const ushort* kp = Ks + (kb + key1) * 24 + quad * 8;
                af1 = ldf(kp);
                af2 = ldf(kp + 96);
            }
            floatx4 s1 = mfma16(af1, qf, zf4);
            floatx4 s2 = mfma16(af2, qf, zf4);
            float p0 = __expf(fminf(s1[0], 50.f)), p1 = __expf(fminf(s1[1], 50.f));
            float p2 = __expf(fminf(s1[2], 50.f)), p3 = __expf(fminf(s1[3], 50.f));
            float p4 = __expf(fminf(s2[0], 50.f)), p5 = __expf(fminf(s2[1], 50.f));
            float p6 = __expf(fminf(s2[2], 50.f)), p7 = __expf(fminf(s2[3], 50.f));
            ll += ((p0 + p1) + (p2 + p3)) + ((p4 + p5) + (p6 + p7));
            short8 pf;
            pf[0] = (short)f2bf(p0); pf[1] = (short)f2bf(p1);
            pf[2] = (short)f2bf(p2); pf[3] = (short)f2bf(p3);
            pf[4] = (short)f2bf(p4); pf[5] = (short)f2bf(p5);
            pf[6] = (short)f2bf(p6); pf[7] = (short)f2bf(p7);
            short8 vf = ldf(Vt + m16 * 536 + kb + quad * 8);
            O = mfma16(vf, pf, O);
        }
        ll += __shfl_xor(ll, 16, 64);
        ll += __shfl_xor(ll, 32, 64);
        float inv = 1.f / ll;
        uint lo = (uint)f2bf(O[0] * inv) | ((uint)f2bf(O[1] * inv) << 16);
        uint hi = (uint)f2bf(O[2] * inv) | ((uint)f2bf(O[3] * inv) << 16);
        uint2 st = {lo, hi};
        *(uint2*)(q + (size_t)qrow * 64 + head * 16 + quad * 4) = st;
    }
}

// ---------------- O-projection + bn(h) residual + BN2 stats, tile-paired ----------------
__global__ void oproj_k(ushort* __restrict__ o, const ushort* __restrict__ h,
                        const float* __restrict__ st3, const ushort* __restrict__ g3,
                        const ushort* __restrict__ b3, int ident,
                        const ushort* __restrict__ Wo, const ushort* __restrict__ bo,
                        float* __restrict__ stats){
    __shared__ __align__(16) ushort As[64 * 72];
    __shared__ __align__(16) ushort Ws[64 * 72];
    __shared__ float sb[128];
    __shared__ float sf[128];
    int t = threadIdx.x;
    bnfin(sf, st3, g3, b3, ident, t);
    if (t < 128) sb[t] = 0.f;
    for (int i = t; i < 2048; i += 256){
        int r = i >> 5, u = i & 31;
        ((uint*)(Ws + r * 72))[u] = ((const uint*)Wo)[i];
    }
    __syncthreads();
    int w = t >> 6, l = t & 63, m = l & 15, q4 = l >> 4;
    for (int tile = 0; tile < 2; ++tile){
        int row0 = blockIdx.x * 128 + tile * 64;
        if (tile) __syncthreads();
        for (int i = t; i < 2048; i += 256){
            int r = i >> 5, u = i & 31;
            ((uint*)(As + r * 72))[u] = ((const uint*)(o + (size_t)row0 * 64))[i];
        }
        __syncthreads();
        const ushort* ap = As + (16 * w + m) * 72 + q4 * 8;
        short8 a0 = ldf(ap), a1 = ldf(ap + 32);
        #pragma unroll
        for (int nt = 0; nt < 4; ++nt){
            const ushort* bp = Ws + (nt * 16 + m) * 72 + q4 * 8;
            floatx4 c = {0.f, 0.f, 0.f, 0.f};
            c = mfma16(a0, ldf(bp), c);
            c = mfma16(a1, ldf(bp + 32), c);
            int ch = nt * 16 + m;
            float bv = bf2f(bo[ch]);
            float ba = sf[ch], bb = sf[64 + ch];
            float vs = 0.f, vss = 0.f;
            #pragma unroll
            for (int r = 0; r < 4; ++r){
                size_t gi = (size_t)(row0 + 16 * w + q4 * 4 + r) * 64 + ch;
                float val = c[r] + bv + ba * bf2f(h[gi]) + bb;
                o[gi] = f2bf(val);
                vs += val; vss += val * val;
            }
            vs  += __shfl_xor(vs, 16, 64);  vs  += __shfl_xor(vs, 32, 64);
            vss += __shfl_xor(vss, 16, 64); vss += __shfl_xor(vss, 32, 64);
            if (q4 == 0){
                atomicAdd(&sb[ch], vs);
                atomicAdd(&sb[64 + ch], vss);
            }
        }
    }
    __syncthreads();
    if (t < 64){
        atomicAdd(&stats[t], sb[t]);
        atomicAdd(&stats[64 + t], sb[64 + t]);
    }
}

// ---------------- comb, tile-paired: weights staged once ----------------
__global__ void comb_k(const ushort* __restrict__ hlpre, const ushort* __restrict__ hapre,
                       const float* __restrict__ st1, const ushort* __restrict__ n1g,
                       const ushort* __restrict__ n1b,
                       const float* __restrict__ st2, const ushort* __restrict__ n2g,
                       const ushort* __restrict__ n2b,
                       const ushort* __restrict__ W1, const ushort* __restrict__ b1,
                       const ushort* __restrict__ W2, const ushort* __restrict__ b2,
                       ushort* __restrict__ hout, float* __restrict__ stats){
    __shared__ __align__(16) ushort Ob[64 * 72];
    __shared__ float Of[64 * 64];
    __shared__ __align__(16) ushort W1s[128 * 72];
    __shared__ __align__(16) ushort Hs[64 * 136];
    __shared__ __align__(16) ushort W2s[64 * 136];
    __shared__ float sb[128];
    __shared__ float sf1[128], sf2[128];
    int t = threadIdx.x;
    if (t < 128){
        const float* st = (t < 64) ? st1 : st2;
        const ushort* g = (t < 64) ? n1g : n2g;
        const ushort* b = (t < 64) ? n1b : n2b;
        float* f = (t < 64) ? sf1 : sf2;
        int c = t & 63;
        float mu  = st[c] * (1.f / NTOT);
        float var = st[64 + c] * (1.f / NTOT) - mu * mu;
        float a = rsqrtf(var + EPSV) * bf2f(g[c]);
        f[c] = a;
        f[64 + c] = bf2f(b[c]) - mu * a;
        sb[t] = 0.f;
    }
    for (int i = t; i < 4096; i += 256){
        int r = i >> 5, u = i & 31;
        ((uint*)(W1s + r * 72))[u] = ((const uint*)W1)[i];
        int r2 = i >> 6, u2 = i & 63;
        ((uint*)(W2s + r2 * 136))[u2] = ((const uint*)W2)[i];
    }
    __syncthreads();
    int w = t >> 6, l = t & 63, m = l & 15, q4 = l >> 4;
    for (int tile = 0; tile < 2; ++tile){
        int row0 = blockIdx.x * 128 + tile * 64;
        if (tile) __syncthreads();
        for (int i = t; i < 2048; i += 256){
            int r = i >> 5, u = i & 31;
            size_t gi = (size_t)(row0 + r) * 32 + u;
            uint wl = ((const uint*)hlpre)[gi], wa = ((const uint*)hapre)[gi];
            int c0 = u * 2;
            float2 pl = bfp2(wl), pa = bfp2(wa);
            float v0 = pl.x * sf1[c0] + sf1[64 + c0] + pa.x * sf2[c0] + sf2[64 + c0];
            float v1 = pl.y * sf1[c0 + 1] + sf1[64 + c0 + 1] + pa.y * sf2[c0 + 1] + sf2[64 + c0 + 1];
            ((uint*)(Ob + r * 72))[u] = (uint)f2bf(v0) | ((uint)f2bf(v1) << 16);
            Of[r * 64 + c0] = v0; Of[r * 64 + c0 + 1] = v1;
        }
        __syncthreads();
        const ushort* ap = Ob + (16 * w + m) * 72 + q4 * 8;
        short8 a0 = ldf(ap), a1 = ldf(ap + 32);
        #pragma unroll
        for (int nt = 0; nt < 8; ++nt){
            const ushort* bp = W1s + (nt * 16 + m) * 72 + q4 * 8;
            floatx4 c = {0.f, 0.f, 0.f, 0.f};
            c = mfma16(a0, ldf(bp), c);
            c = mfma16(a1, ldf(bp + 32), c);
            float bv = bf2f(b1[nt * 16 + m]);
            #pragma unroll
            for (int r = 0; r < 4; ++r)
                Hs[(16 * w + q4 * 4 + r) * 136 + nt * 16 + m] = f2bf(fmaxf(c[r] + bv, 0.f));
        }
        const ushort* ap2 = Hs + (16 * w + m) * 136 + q4 * 8;
        short8 h0 = ldf(ap2), h1 = ldf(ap2 + 32), h2 = ldf(ap2 + 64), h3 = ldf(ap2 + 96);
        #pragma unroll
        for (int nt = 0; nt < 4; ++nt){
            const ushort* bp = W2s + (nt * 16 + m) * 136 + q4 * 8;
            floatx4 c = {0.f, 0.f, 0.f, 0.f};
            c = mfma16(h0, ldf(bp), c);
            c = mfma16(h1, ldf(bp + 32), c);
            c = mfma16(h2, ldf(bp + 64), c);
            c = mfma16(h3, ldf(bp + 96), c);
            float bv = bf2f(b2[nt * 16 + m]);
            float vs = 0.f, vss = 0.f;
            #pragma unroll
            for (int r = 0; r < 4; ++r){
                int lr = 16 * w + q4 * 4 + r;
                float val = c[r] + bv + Of[lr * 64 + nt * 16 + m];
                hout[(size_t)(row0 + lr) * 64 + nt * 16 + m] = f2bf(val);
                vs += val; vss += val * val;
            }
            vs  += __shfl_xor(vs, 16, 64);  vs  += __shfl_xor(vs, 32, 64);
            vss += __shfl_xor(vss, 16, 64); vss += __shfl_xor(vss, 32, 64);
            if (q4 == 0){
                atomicAdd(&sb[nt * 16 + m], vs);
                atomicAdd(&sb[64 + nt * 16 + m], vss);
            }
        }
    }
    __syncthreads();
    if (t < 64){
        atomicAdd(&stats[t], sb[t]);
        atomicAdd(&stats[64 + t], sb[64 + t]);
    }
}

// ---------------- mean pool (pre-BN h + affine post) + head GEMM ----------------
__global__ void pool_head_k(const ushort* __restrict__ h, const float* __restrict__ st3,
                            const ushort* __restrict__ g3, const ushort* __restrict__ b3,
                            const ushort* __restrict__ Wh, const ushort* __restrict__ bh,
                            const int* __restrict__ flag, void* __restrict__ out){
    __shared__ float red[256];
    __shared__ float pooled[64];
    __shared__ float sf[128];
    int t = threadIdx.x, g = blockIdx.x;
    bnfin(sf, st3, g3, b3, 0, t);
    int c = t & 63, rb = t >> 6;
    float s = 0.f;
    for (int ii = 0; ii < 128; ++ii){
        int r = rb + 4 * ii;
        s += bf2f(h[(size_t)(g * 512 + r) * 64 + c]);
    }
    red[t] = s; __syncthreads();
    if (t < 64)
        pooled[t] = sf[t] * ((red[t] + red[64 + t] + red[128 + t] + red[192 + t]) * (1.f / 512.f))
                  + sf[64 + t];
    __syncthreads();
    if (t < 128){
        float a = bf2f(bh[t]);
        #pragma unroll
        for (int k = 0; k < 64; ++k) a += pooled[k] * bf2f(Wh[t * 64 + k]);
        if (*flag) ((ushort*)out)[(size_t)g * 128 + t] = f2bf(a);
        else       ((float*)out)[(size_t)g * 128 + t] = a;
    }
}

extern "C" void kernel_launch(void* const* d_in, const int* in_sizes, int n_in,
                              void* d_out, int out_size, void* d_ws, size_t ws_size,
                              hipStream_t stream){
    const void* x  = d_in[0];
    const void* pe = d_in[1];
    const int* eidx = (const int*)d_in[2];

    char* ws = (char*)d_ws;
    const size_t MB = 1024 * 1024;
    const size_t KB = 1024;
    ushort* h_buf = (ushort*)(ws);
    ushort* z_buf = (ushort*)(ws + 8 * MB);
    ushort* q_buf = (ushort*)(ws + 16 * MB);
    ushort* k_buf = (ushort*)(ws + 24 * MB);
    ushort* v_buf = (ushort*)(ws + 32 * MB);
    int* csr   = (int*)(ws + 40 * MB);
    int* offs  = (int*)(ws + 44 * MB);
    int* cnt   = (int*)(ws + 44 * MB + 384 * KB);
    int* cur   = (int*)(ws + 44 * MB + 640 * KB);
    float* stats = (float*)(ws + 44 * MB + 896 * KB);
    float* fin   = (float*)(ws + 44 * MB + 904 * KB);
    int*   flag  = (int*)(ws + 44 * MB + 912 * KB);
    ushort* wsa  = (ushort*)(ws + 45 * MB);

    hipMemsetAsync(stats, 0, 13 * 128 * sizeof(float), stream);
    hipMemsetAsync(cnt, 0, 65536 * sizeof(int), stream);

    detect_k<<<1, 64, 0, stream>>>((const uint*)x, flag);

    WPtrs wp;
    for (int i = 0; i < 30; ++i) wp.p[i] = d_in[3 + i];
    convall_k<<<(TOTW + 255) / 256, 256, 0, stream>>>(wp, wsa, flag);

    pe_stats_k<<<256, 256, 0, stream>>>(pe, flag, stats);
    fin_k<<<1, 64, 0, stream>>>(stats, wsa + OG_PEN, wsa + OB_PEN, fin, 16);
    embed_k<<<1024, 256, 0, stream>>>(x, pe, flag, wsa, fin, h_buf);
    hist_k<<<1024, 256, 0, stream>>>(eidx + NEDGE, cnt);
    scan_k<<<1, 1024, 0, stream>>>(cnt, offs, cur);
    scatter_k<<<1024, 256, 0, stream>>>(eidx, eidx + NEDGE, cur, csr);

    for (int l = 0; l < NLAYER; ++l){
        float* st1 = stats + (1 + 3 * l) * 128;
        float* st2 = stats + (2 + 3 * l) * 128;
        float* st3 = stats + (3 + 3 * l) * 128;
        int ident = (l == 0) ? 1 : 0;
        const float* stp = (l == 0) ? stats : stats + (3 * l) * 128;
        const ushort* gp = wsa + ON3G + (l ? (l - 1) : 0) * 64;
        const ushort* bp = wsa + ON3B + (l ? (l - 1) : 0) * 64;

        agg_k<<<8192, 256, 0, stream>>>(h_buf, offs, csr, z_buf, stp, gp, bp, ident);
        ginqkv_k<<<512, 256, 0, stream>>>(z_buf, h_buf, stp, gp, bp, ident,
                                          wsa + OW_G1 + l * 4096, wsa + OB_G1 + l * 64,
                                          wsa + OW_G2 + l * 4096, wsa + OB_G2 + l * 64,
                                          wsa + OW_Q + l * 4096, wsa + OB_Q + l * 64,
                                          wsa + OW_K + l * 4096, wsa + OB_K + l * 64,
                                          wsa + OW_V + l * 4096, wsa + OB_V + l * 64,
                                          z_buf, q_buf, k_buf, v_buf, st1);
        attn_k<<<512, 256, 0, stream>>>(q_buf, k_buf, v_buf);
        oproj_k<<<512, 256, 0, stream>>>(q_buf, h_buf, stp, gp, bp, ident,
                                         wsa + OW_O + l * 4096, wsa + OB_O + l * 64, st2);
        comb_k<<<512, 256, 0, stream>>>(z_buf, q_buf,
                                        st1, wsa + ON1G + l * 64, wsa + ON1B + l * 64,
                                        st2, wsa + ON2G + l * 64, wsa + ON2B + l * 64,
                                        wsa + OW_M1 + l * 8192, wsa + OB_M1 + l * 128,
                                        wsa + OW_M2 + l * 8192, wsa + OB_M2 + l * 64,
                                        h_buf, st3);
    }
    pool_head_k<<<128, 256, 0, stream>>>(h_buf, stats + 12 * 128,
                                         wsa + ON3G + 3 * 64, wsa + ON3B + 3 * 64,
                                         wsa + OW_H, wsa + OB_H, flag, d_out);
}